// Round 1
// baseline (1848.527 us; speedup 1.0000x reference)
//
#include <hip/hip_runtime.h>
#include <math.h>

#define B 8
#define S 1024
#define HID 768
#define RH 384
#define NH 6
#define HD 64
#define KW 9
#define KNH 54
#define OUTHALF 384

// ---------------- generic tiled f32 GEMM: C = A @ B (+bias), optional B transposed ----------------
// A [M,Kd] row-major. BT=false: B [Kd,N]. BT=true: B [N,Kd] (C = A @ B^T).
// C written with row stride ldc (C[m*ldc + n]).
template<bool BT>
__global__ __launch_bounds__(256) void gemm_bias(
    const float* __restrict__ A, const float* __restrict__ Bm,
    const float* __restrict__ bias, float* __restrict__ C,
    int M, int N, int Kd, int ldc)
{
    __shared__ float As[16][64];
    __shared__ float Bs[16][65];
    const int t = threadIdx.x;
    const int bm = blockIdx.y * 64;
    const int bn = blockIdx.x * 64;
    const int tx = t & 15, ty = t >> 4;
    float acc[4][4] = {};
    for (int k0 = 0; k0 < Kd; k0 += 16) {
        {
            int m = t >> 2, kk = (t & 3) << 2;
            const float4 av = *(const float4*)(A + (size_t)(bm + m) * Kd + k0 + kk);
            As[kk+0][m] = av.x; As[kk+1][m] = av.y; As[kk+2][m] = av.z; As[kk+3][m] = av.w;
        }
        if (!BT) {
            int n = t & 63, kb = t >> 6;
            int gn = bn + n;
            #pragma unroll
            for (int i = 0; i < 4; i++) {
                int kk = kb + i*4;
                Bs[kk][n] = (gn < N) ? Bm[(size_t)(k0+kk)*N + gn] : 0.f;
            }
        } else {
            int n = t >> 2, kk = (t & 3) << 2;
            int gn = bn + n;
            if (gn < N) {
                const float4 bv = *(const float4*)(Bm + (size_t)gn * Kd + k0 + kk);
                Bs[kk+0][n] = bv.x; Bs[kk+1][n] = bv.y; Bs[kk+2][n] = bv.z; Bs[kk+3][n] = bv.w;
            } else {
                Bs[kk+0][n] = 0.f; Bs[kk+1][n] = 0.f; Bs[kk+2][n] = 0.f; Bs[kk+3][n] = 0.f;
            }
        }
        __syncthreads();
        #pragma unroll
        for (int kk = 0; kk < 16; kk++) {
            float a[4], bb[4];
            #pragma unroll
            for (int i = 0; i < 4; i++) a[i] = As[kk][ty*4+i];
            #pragma unroll
            for (int j = 0; j < 4; j++) bb[j] = Bs[kk][tx*4+j];
            #pragma unroll
            for (int i = 0; i < 4; i++)
                #pragma unroll
                for (int j = 0; j < 4; j++)
                    acc[i][j] += a[i]*bb[j];
        }
        __syncthreads();
    }
    #pragma unroll
    for (int i = 0; i < 4; i++) {
        int m = bm + ty*4 + i;
        #pragma unroll
        for (int j = 0; j < 4; j++) {
            int n = bn + tx*4 + j;
            if (n < N) C[(size_t)m*ldc + n] = acc[i][j] + bias[n];
        }
    }
}

// ---------------- depthwise conv along seq (same pad), output layout [B,S,HID] ----------------
__global__ __launch_bounds__(256) void dwconv_kernel(
    const float* __restrict__ key, const float* __restrict__ dw_w,
    const float* __restrict__ dw_b, float* __restrict__ dwout)
{
    int idx = blockIdx.x*256 + threadIdx.x;
    if (idx >= B*S*HID) return;
    int hh = idx % HID;
    int s  = (idx / HID) % S;
    int b  = idx / (HID*S);
    float acc = dw_b[hh];
    #pragma unroll
    for (int kk = 0; kk < KW; kk++) {
        int sp = s + kk - KW/2;
        if (sp >= 0 && sp < S)
            acc += key[((size_t)b*S + sp)*HID + hh] * dw_w[hh*KW + kk];
    }
    dwout[idx] = acc;
}

// ---------------- attention pass 1: raw scores -> out0, online logsumexp stats ----------------
__global__ __launch_bounds__(256) void attn_scores(
    const float* __restrict__ q, const float* __restrict__ k,
    const int* __restrict__ mask, float* __restrict__ out0,
    float* __restrict__ stats)
{
    __shared__ float Qs[32][65];
    __shared__ float Ks[64][65];
    const int b = blockIdx.z, h = blockIdx.y, q0 = blockIdx.x*32;
    const int t = threadIdx.x;
    for (int idx = t; idx < 32*64; idx += 256) {
        int r = idx >> 6, d = idx & 63;
        Qs[r][d] = q[((size_t)b*S + q0 + r)*RH + h*HD + d];
    }
    const int r = t >> 3, cg = t & 7;
    float mrow = -INFINITY, ssum = 0.f;
    const size_t orow = ((size_t)(b*NH + h)*S + q0 + r)*S;
    for (int kc = 0; kc < S; kc += 64) {
        __syncthreads();
        for (int idx = t; idx < 64*64; idx += 256) {
            int c = idx >> 6, d = idx & 63;
            Ks[c][d] = k[((size_t)b*S + kc + c)*RH + h*HD + d];
        }
        __syncthreads();
        #pragma unroll
        for (int j = 0; j < 8; j++) {
            int c = cg*8 + j;
            float acc = 0.f;
            #pragma unroll
            for (int d = 0; d < 64; d++) acc += Qs[r][d]*Ks[c][d];
            acc *= 0.125f;
            if (mask[b*S + kc + c] == 0) acc = -INFINITY;
            out0[orow + kc + c] = acc;
            float nm = fmaxf(mrow, acc);
            if (nm != -INFINITY) {
                ssum = ssum*__expf(mrow - nm) + __expf(acc - nm);
                mrow = nm;
            }
        }
    }
    // reduce (m, sum) across the 8 threads covering this row
    #pragma unroll
    for (int off = 1; off < 8; off <<= 1) {
        float om = __shfl_xor(mrow, off, 8);
        float os = __shfl_xor(ssum, off, 8);
        float nm = fmaxf(mrow, om);
        if (nm != -INFINITY) {
            ssum = ssum*__expf(mrow - nm) + os*__expf(om - nm);
        } else {
            ssum = 0.f;
        }
        mrow = nm;
    }
    if (cg == 0) {
        size_t ridx = (size_t)(b*NH + h)*S + q0 + r;
        stats[ridx*2]   = mrow;
        stats[ridx*2+1] = ssum;
    }
}

// ---------------- attention pass 2: normalize in-place + P@V ----------------
__global__ __launch_bounds__(256) void attn_pv(
    float* __restrict__ out0, const float* __restrict__ v,
    const float* __restrict__ stats, float* __restrict__ attnws)
{
    __shared__ float Vs[64][65];
    __shared__ float Ps[32][65];
    __shared__ float Ms[32], Is[32];
    const int b = blockIdx.z, h = blockIdx.y, q0 = blockIdx.x*32;
    const int t = threadIdx.x;
    const size_t rbase = (size_t)(b*NH + h)*S + q0;
    if (t < 32) {
        Ms[t] = stats[(rbase + t)*2];
        Is[t] = 1.f / stats[(rbase + t)*2 + 1];
    }
    const int r = t >> 3, d0 = (t & 7)*8;
    float acc[8] = {};
    for (int kc = 0; kc < S; kc += 64) {
        __syncthreads();
        for (int idx = t; idx < 64*64; idx += 256) {
            int c = idx >> 6, d = idx & 63;
            Vs[c][d] = v[((size_t)b*S + kc + c)*RH + h*HD + d];
        }
        for (int idx = t; idx < 32*64; idx += 256) {
            int rr = idx >> 6, c = idx & 63;
            size_t gi = (rbase + rr)*S + kc + c;
            float p = __expf(out0[gi] - Ms[rr]) * Is[rr];
            out0[gi] = p;
            Ps[rr][c] = p;
        }
        __syncthreads();
        #pragma unroll
        for (int c = 0; c < 64; c++) {
            float pv = Ps[r][c];
            #pragma unroll
            for (int j = 0; j < 8; j++) acc[j] += pv * Vs[c][d0+j];
        }
    }
    #pragma unroll
    for (int j = 0; j < 8; j++)
        attnws[((size_t)b*S + q0 + r)*RH + h*HD + d0 + j] = acc[j];
}

// ---------------- elementwise q * ks_feat ----------------
__global__ __launch_bounds__(256) void qks_kernel(
    const float* __restrict__ a, const float* __restrict__ b2,
    float* __restrict__ c, int n)
{
    int i = blockIdx.x*256 + threadIdx.x;
    if (i < n) c[i] = a[i]*b2[i];
}

// ---------------- dynamic conv: softmax over K taps, then 9-tap conv of v ----------------
__global__ __launch_bounds__(256) void dyn_conv(
    const float* __restrict__ logits, const float* __restrict__ v,
    float* __restrict__ dynout)
{
    int idx = blockIdx.x*256 + threadIdx.x;
    if (idx >= B*S*RH) return;
    int rr = idx % RH;
    int s  = (idx / RH) % S;
    int b  = idx / (RH*S);
    int h  = rr / HD;
    const float* lg = logits + ((size_t)b*S + s)*KNH + h*KW;
    float mx = lg[0];
    #pragma unroll
    for (int kk = 1; kk < KW; kk++) mx = fmaxf(mx, lg[kk]);
    float e[KW], sum = 0.f;
    #pragma unroll
    for (int kk = 0; kk < KW; kk++) { e[kk] = __expf(lg[kk]-mx); sum += e[kk]; }
    float inv = 1.f/sum;
    float acc = 0.f;
    #pragma unroll
    for (int kk = 0; kk < KW; kk++) {
        int sp = s + kk - KW/2;
        if (sp >= 0 && sp < S)
            acc += v[((size_t)b*S + sp)*RH + rr] * e[kk];
    }
    dynout[idx] = acc*inv;
}

extern "C" void kernel_launch(void* const* d_in, const int* in_sizes, int n_in,
                              void* d_out, int out_size, void* d_ws, size_t ws_size,
                              hipStream_t stream) {
    const float* query = (const float*)d_in[0];
    const int*   mask  = (const int*)d_in[1];
    const float* Wq    = (const float*)d_in[2];
    const float* bq    = (const float*)d_in[3];
    const float* Wk    = (const float*)d_in[4];
    const float* bk    = (const float*)d_in[5];
    const float* Wv    = (const float*)d_in[6];
    const float* bv    = (const float*)d_in[7];
    const float* dw_w  = (const float*)d_in[8];
    const float* dw_b  = (const float*)d_in[9];
    const float* pw_w  = (const float*)d_in[10];
    const float* pw_b  = (const float*)d_in[11];
    const float* Wsa   = (const float*)d_in[12];
    const float* bsa   = (const float*)d_in[13];
    const float* Wdk   = (const float*)d_in[14];
    const float* bdk   = (const float*)d_in[15];
    const float* Wda   = (const float*)d_in[16];
    const float* bda   = (const float*)d_in[17];
    const float* key   = (const float*)d_in[18];
    const float* value = (const float*)d_in[19];

    float* out0 = (float*)d_out;                         // attn_wts [B,NH,S,S]
    float* out1 = out0 + (size_t)B*NH*S*S;               // concat [B,S,HID]

    // workspace layout (floats). Total ~22.6M floats ~= 90 MB.
    float* ws     = (float*)d_ws;
    float* q      = ws;
    float* k      = q      + (size_t)B*S*RH;
    float* v      = k      + (size_t)B*S*RH;
    float* ksf    = v      + (size_t)B*S*RH;
    float* attnws = ksf    + (size_t)B*S*RH;
    float* dynlog = attnws + (size_t)B*S*RH;
    float* stats  = dynlog + (size_t)B*S*KNH;
    float* X      = stats  + (size_t)B*NH*S*2;   // 6.29M floats: dw, later qks+dynout
    float* qks    = X;                            // reuses dw space after ksf done
    float* dynout = X + (size_t)B*S*RH;

    dim3 g64(RH/64, (B*S)/64);

    // q/k/v projections
    gemm_bias<false><<<g64, 256, 0, stream>>>(query, Wq, bq, q, B*S, RH, HID, RH);
    gemm_bias<false><<<g64, 256, 0, stream>>>(key,   Wk, bk, k, B*S, RH, HID, RH);
    gemm_bias<false><<<g64, 256, 0, stream>>>(value, Wv, bv, v, B*S, RH, HID, RH);

    // depthwise conv (to [B,S,HID]) then pointwise: ksf = dw @ pw_w^T + pw_b
    dwconv_kernel<<<(B*S*HID + 255)/256, 256, 0, stream>>>(key, dw_w, dw_b, X);
    gemm_bias<true><<<g64, 256, 0, stream>>>(X, pw_w, pw_b, ksf, B*S, RH, HID, RH);

    // attention
    dim3 ga(S/32, NH, B);
    attn_scores<<<ga, 256, 0, stream>>>(q, k, mask, out0, stats);
    attn_pv<<<ga, 256, 0, stream>>>(out0, v, stats, attnws);

    // self-attn output projection -> out1[:, :384]
    gemm_bias<false><<<g64, 256, 0, stream>>>(attnws, Wsa, bsa, out1, B*S, OUTHALF, RH, HID);

    // dynamic branch
    int nq = B*S*RH;
    qks_kernel<<<(nq + 255)/256, 256, 0, stream>>>(q, ksf, qks, nq);
    dim3 gdl(1, (B*S)/64);
    gemm_bias<false><<<gdl, 256, 0, stream>>>(qks, Wdk, bdk, dynlog, B*S, KNH, RH, KNH);
    dyn_conv<<<(nq + 255)/256, 256, 0, stream>>>(dynlog, v, dynout);
    gemm_bias<false><<<g64, 256, 0, stream>>>(dynout, Wda, bda, out1 + OUTHALF, B*S, OUTHALF, RH, HID);
}

// Round 2
// 796.199 us; speedup vs baseline: 2.3217x; 2.3217x over previous
//
#include <hip/hip_runtime.h>
#include <math.h>

#define B 8
#define S 1024
#define HID 768
#define RH 384
#define NH 6
#define HD 64
#define KW 9
#define KNH 54
#define OUTHALF 384

typedef __attribute__((ext_vector_type(8))) short short8;
typedef __attribute__((ext_vector_type(4))) float f32x4;

// element-index XOR swizzle for [R][64] ushort LDS tiles (breaks 128B-row bank conflicts)
#define SWZ(r, c) (((r) << 6) + ((c) ^ (((r) & 7) << 3)))

__device__ __forceinline__ ushort f2bf(float x) {
    unsigned u = __float_as_uint(x);
    u += 0x7FFF + ((u >> 16) & 1);
    return (ushort)(u >> 16);
}

__device__ __forceinline__ short8 cvt8(const float* p) {
    short8 r;
    #pragma unroll
    for (int i = 0; i < 8; i++) r[i] = (short)f2bf(p[i]);
    return r;
}

// ---------------- fused attention: QK^T (MFMA) -> softmax -> write attn_wts -> PV (MFMA) ----------------
__global__ __launch_bounds__(256) void attn_fused(
    const float* __restrict__ q, const float* __restrict__ k,
    const float* __restrict__ v, const int* __restrict__ mask,
    float* __restrict__ out0, float* __restrict__ attnws)
{
    __shared__ ushort Ks[64*64];     // [key][d] bf16, swizzled
    __shared__ ushort Vt[64*64];     // [d][key] bf16, swizzled
    __shared__ ushort Ps[4][16*64];  // per-wave P tile [qrow][key], swizzled

    const int b = blockIdx.z, h = blockIdx.y, q0 = blockIdx.x * 64;
    const int t = threadIdx.x;
    const int wave = t >> 6, lane = t & 63;
    const int lr = lane & 15, lg = lane >> 4;

    // Q fragments (A operand), kept in registers for the whole kernel
    const float* qrow = q + ((size_t)(b*S + q0 + wave*16 + lr))*RH + h*HD;
    float qb[8];
    *(float4*)&qb[0] = *(const float4*)(qrow + lg*8);
    *(float4*)&qb[4] = *(const float4*)(qrow + lg*8 + 4);
    short8 aQ0 = cvt8(qb);
    *(float4*)&qb[0] = *(const float4*)(qrow + 32 + lg*8);
    *(float4*)&qb[4] = *(const float4*)(qrow + 32 + lg*8 + 4);
    short8 aQ1 = cvt8(qb);

    const int srow = t >> 2;   // staging: key row (K) or d row (Vt)
    const int sseg = t & 3;
    const int* mrow = mask + b*S;

    float lsum[4] = {0.f, 0.f, 0.f, 0.f};

    // ---------------- pass A: softmax denominators ----------------
    for (int kc = 0; kc < S; kc += 64) {
        __syncthreads();
        {   // stage K tile -> bf16 LDS
            const float* kr = k + ((size_t)(b*S + kc + srow))*RH + h*HD + sseg*16;
            float kb[16];
            *(float4*)&kb[0]  = *(const float4*)(kr);
            *(float4*)&kb[4]  = *(const float4*)(kr + 4);
            *(float4*)&kb[8]  = *(const float4*)(kr + 8);
            *(float4*)&kb[12] = *(const float4*)(kr + 12);
            *(short8*)&Ks[SWZ(srow, sseg*16)]     = cvt8(kb);
            *(short8*)&Ks[SWZ(srow, sseg*16 + 8)] = cvt8(kb + 8);
        }
        __syncthreads();
        #pragma unroll
        for (int t4 = 0; t4 < 4; t4++) {
            short8 b0 = *(const short8*)&Ks[SWZ(t4*16 + lr, lg*8)];
            short8 b1 = *(const short8*)&Ks[SWZ(t4*16 + lr, 32 + lg*8)];
            f32x4 c = {0.f, 0.f, 0.f, 0.f};
            c = __builtin_amdgcn_mfma_f32_16x16x32_bf16(aQ0, b0, c, 0, 0, 0);
            c = __builtin_amdgcn_mfma_f32_16x16x32_bf16(aQ1, b1, c, 0, 0, 0);
            float add = mrow[kc + t4*16 + lr] ? 0.f : -1e30f;
            #pragma unroll
            for (int r = 0; r < 4; r++)
                lsum[r] += __expf(c[r]*0.125f + add);
        }
    }
    #pragma unroll
    for (int r = 0; r < 4; r++) {
        #pragma unroll
        for (int off = 1; off < 16; off <<= 1)
            lsum[r] += __shfl_xor(lsum[r], off, 16);
    }
    float inv[4];
    #pragma unroll
    for (int r = 0; r < 4; r++) inv[r] = 1.f / lsum[r];

    // ---------------- pass B: recompute, normalize, write P, PV ----------------
    f32x4 o[4] = {};
    ushort* Psw = &Ps[wave][0];
    const size_t obase = ((size_t)((b*NH + h)*S) + q0 + wave*16) * (size_t)S;

    for (int kc = 0; kc < S; kc += 64) {
        __syncthreads();
        {   // stage K tile
            const float* kr = k + ((size_t)(b*S + kc + srow))*RH + h*HD + sseg*16;
            float kb[16];
            *(float4*)&kb[0]  = *(const float4*)(kr);
            *(float4*)&kb[4]  = *(const float4*)(kr + 4);
            *(float4*)&kb[8]  = *(const float4*)(kr + 8);
            *(float4*)&kb[12] = *(const float4*)(kr + 12);
            *(short8*)&Ks[SWZ(srow, sseg*16)]     = cvt8(kb);
            *(short8*)&Ks[SWZ(srow, sseg*16 + 8)] = cvt8(kb + 8);
        }
        {   // stage V tile transposed: Vt[d][key]
            const int d = srow;
            float vb[16];
            #pragma unroll
            for (int i = 0; i < 16; i++)
                vb[i] = v[((size_t)(b*S + kc + sseg*16 + i))*RH + h*HD + d];
            *(short8*)&Vt[SWZ(d, sseg*16)]     = cvt8(vb);
            *(short8*)&Vt[SWZ(d, sseg*16 + 8)] = cvt8(vb + 8);
        }
        __syncthreads();

        #pragma unroll
        for (int t4 = 0; t4 < 4; t4++) {
            short8 b0 = *(const short8*)&Ks[SWZ(t4*16 + lr, lg*8)];
            short8 b1 = *(const short8*)&Ks[SWZ(t4*16 + lr, 32 + lg*8)];
            f32x4 c = {0.f, 0.f, 0.f, 0.f};
            c = __builtin_amdgcn_mfma_f32_16x16x32_bf16(aQ0, b0, c, 0, 0, 0);
            c = __builtin_amdgcn_mfma_f32_16x16x32_bf16(aQ1, b1, c, 0, 0, 0);
            float add = mrow[kc + t4*16 + lr] ? 0.f : -1e30f;
            #pragma unroll
            for (int r = 0; r < 4; r++) {
                float p = __expf(c[r]*0.125f + add) * inv[r];
                out0[obase + (size_t)(lg*4 + r)*S + kc + t4*16 + lr] = p;
                Psw[SWZ(lg*4 + r, t4*16 + lr)] = f2bf(p);
            }
        }
        // PV: O += P @ V
        #pragma unroll
        for (int kh = 0; kh < 2; kh++) {
            short8 pa = *(const short8*)&Psw[SWZ(lr, kh*32 + lg*8)];
            #pragma unroll
            for (int dt = 0; dt < 4; dt++) {
                short8 vb = *(const short8*)&Vt[SWZ(dt*16 + lr, kh*32 + lg*8)];
                o[dt] = __builtin_amdgcn_mfma_f32_16x16x32_bf16(pa, vb, o[dt], 0, 0, 0);
            }
        }
    }

    #pragma unroll
    for (int dt = 0; dt < 4; dt++)
        #pragma unroll
        for (int r = 0; r < 4; r++)
            attnws[((size_t)(b*S + q0 + wave*16 + lg*4 + r))*RH + h*HD + dt*16 + lr] = o[dt][r];
}

// ---------------- generic tiled f32 GEMM: C = A @ B (+bias), optional B transposed ----------------
template<bool BT>
__global__ __launch_bounds__(256) void gemm_bias(
    const float* __restrict__ A, const float* __restrict__ Bm,
    const float* __restrict__ bias, float* __restrict__ C,
    int M, int N, int Kd, int ldc)
{
    __shared__ float As[16][64];
    __shared__ float Bs[16][65];
    const int t = threadIdx.x;
    const int bm = blockIdx.y * 64;
    const int bn = blockIdx.x * 64;
    const int tx = t & 15, ty = t >> 4;
    float acc[4][4] = {};
    for (int k0 = 0; k0 < Kd; k0 += 16) {
        {
            int m = t >> 2, kk = (t & 3) << 2;
            const float4 av = *(const float4*)(A + (size_t)(bm + m) * Kd + k0 + kk);
            As[kk+0][m] = av.x; As[kk+1][m] = av.y; As[kk+2][m] = av.z; As[kk+3][m] = av.w;
        }
        if (!BT) {
            int n = t & 63, kb = t >> 6;
            int gn = bn + n;
            #pragma unroll
            for (int i = 0; i < 4; i++) {
                int kk = kb + i*4;
                Bs[kk][n] = (gn < N) ? Bm[(size_t)(k0+kk)*N + gn] : 0.f;
            }
        } else {
            int n = t >> 2, kk = (t & 3) << 2;
            int gn = bn + n;
            if (gn < N) {
                const float4 bv = *(const float4*)(Bm + (size_t)gn * Kd + k0 + kk);
                Bs[kk+0][n] = bv.x; Bs[kk+1][n] = bv.y; Bs[kk+2][n] = bv.z; Bs[kk+3][n] = bv.w;
            } else {
                Bs[kk+0][n] = 0.f; Bs[kk+1][n] = 0.f; Bs[kk+2][n] = 0.f; Bs[kk+3][n] = 0.f;
            }
        }
        __syncthreads();
        #pragma unroll
        for (int kk = 0; kk < 16; kk++) {
            float a[4], bb[4];
            #pragma unroll
            for (int i = 0; i < 4; i++) a[i] = As[kk][ty*4+i];
            #pragma unroll
            for (int j = 0; j < 4; j++) bb[j] = Bs[kk][tx*4+j];
            #pragma unroll
            for (int i = 0; i < 4; i++)
                #pragma unroll
                for (int j = 0; j < 4; j++)
                    acc[i][j] += a[i]*bb[j];
        }
        __syncthreads();
    }
    #pragma unroll
    for (int i = 0; i < 4; i++) {
        int m = bm + ty*4 + i;
        #pragma unroll
        for (int j = 0; j < 4; j++) {
            int n = bn + tx*4 + j;
            if (n < N) C[(size_t)m*ldc + n] = acc[i][j] + bias[n];
        }
    }
}

// ---------------- depthwise conv along seq ----------------
__global__ __launch_bounds__(256) void dwconv_kernel(
    const float* __restrict__ key, const float* __restrict__ dw_w,
    const float* __restrict__ dw_b, float* __restrict__ dwout)
{
    int idx = blockIdx.x*256 + threadIdx.x;
    if (idx >= B*S*HID) return;
    int hh = idx % HID;
    int s  = (idx / HID) % S;
    int b  = idx / (HID*S);
    float acc = dw_b[hh];
    #pragma unroll
    for (int kk = 0; kk < KW; kk++) {
        int sp = s + kk - KW/2;
        if (sp >= 0 && sp < S)
            acc += key[((size_t)b*S + sp)*HID + hh] * dw_w[hh*KW + kk];
    }
    dwout[idx] = acc;
}

// ---------------- elementwise q * ks_feat ----------------
__global__ __launch_bounds__(256) void qks_kernel(
    const float* __restrict__ a, const float* __restrict__ b2,
    float* __restrict__ c, int n)
{
    int i = blockIdx.x*256 + threadIdx.x;
    if (i < n) c[i] = a[i]*b2[i];
}

// ---------------- dynamic conv ----------------
__global__ __launch_bounds__(256) void dyn_conv(
    const float* __restrict__ logits, const float* __restrict__ v,
    float* __restrict__ dynout)
{
    int idx = blockIdx.x*256 + threadIdx.x;
    if (idx >= B*S*RH) return;
    int rr = idx % RH;
    int s  = (idx / RH) % S;
    int b  = idx / (RH*S);
    int h  = rr / HD;
    const float* lg = logits + ((size_t)b*S + s)*KNH + h*KW;
    float mx = lg[0];
    #pragma unroll
    for (int kk = 1; kk < KW; kk++) mx = fmaxf(mx, lg[kk]);
    float e[KW], sum = 0.f;
    #pragma unroll
    for (int kk = 0; kk < KW; kk++) { e[kk] = __expf(lg[kk]-mx); sum += e[kk]; }
    float inv = 1.f/sum;
    float acc = 0.f;
    #pragma unroll
    for (int kk = 0; kk < KW; kk++) {
        int sp = s + kk - KW/2;
        if (sp >= 0 && sp < S)
            acc += v[((size_t)b*S + sp)*RH + rr] * e[kk];
    }
    dynout[idx] = acc*inv;
}

extern "C" void kernel_launch(void* const* d_in, const int* in_sizes, int n_in,
                              void* d_out, int out_size, void* d_ws, size_t ws_size,
                              hipStream_t stream) {
    const float* query = (const float*)d_in[0];
    const int*   mask  = (const int*)d_in[1];
    const float* Wq    = (const float*)d_in[2];
    const float* bq    = (const float*)d_in[3];
    const float* Wk    = (const float*)d_in[4];
    const float* bk    = (const float*)d_in[5];
    const float* Wv    = (const float*)d_in[6];
    const float* bv    = (const float*)d_in[7];
    const float* dw_w  = (const float*)d_in[8];
    const float* dw_b  = (const float*)d_in[9];
    const float* pw_w  = (const float*)d_in[10];
    const float* pw_b  = (const float*)d_in[11];
    const float* Wsa   = (const float*)d_in[12];
    const float* bsa   = (const float*)d_in[13];
    const float* Wdk   = (const float*)d_in[14];
    const float* bdk   = (const float*)d_in[15];
    const float* Wda   = (const float*)d_in[16];
    const float* bda   = (const float*)d_in[17];
    const float* key   = (const float*)d_in[18];
    const float* value = (const float*)d_in[19];

    float* out0 = (float*)d_out;                         // attn_wts [B,NH,S,S]
    float* out1 = out0 + (size_t)B*NH*S*S;               // concat [B,S,HID]

    float* ws     = (float*)d_ws;
    float* q      = ws;
    float* k      = q      + (size_t)B*S*RH;
    float* v      = k      + (size_t)B*S*RH;
    float* ksf    = v      + (size_t)B*S*RH;
    float* attnws = ksf    + (size_t)B*S*RH;
    float* dynlog = attnws + (size_t)B*S*RH;
    float* stats  = dynlog + (size_t)B*S*KNH;
    float* X      = stats  + (size_t)B*NH*S*2;
    float* qks    = X;
    float* dynout = X + (size_t)B*S*RH;

    dim3 g64(RH/64, (B*S)/64);

    // q/k/v projections
    gemm_bias<false><<<g64, 256, 0, stream>>>(query, Wq, bq, q, B*S, RH, HID, RH);
    gemm_bias<false><<<g64, 256, 0, stream>>>(key,   Wk, bk, k, B*S, RH, HID, RH);
    gemm_bias<false><<<g64, 256, 0, stream>>>(value, Wv, bv, v, B*S, RH, HID, RH);

    // depthwise conv then pointwise
    dwconv_kernel<<<(B*S*HID + 255)/256, 256, 0, stream>>>(key, dw_w, dw_b, X);
    gemm_bias<true><<<g64, 256, 0, stream>>>(X, pw_w, pw_b, ksf, B*S, RH, HID, RH);

    // fused MFMA attention
    dim3 ga(S/64, NH, B);
    attn_fused<<<ga, 256, 0, stream>>>(q, k, v, mask, out0, attnws);

    // self-attn output projection -> out1[:, :384]
    gemm_bias<false><<<g64, 256, 0, stream>>>(attnws, Wsa, bsa, out1, B*S, OUTHALF, RH, HID);

    // dynamic branch
    int nq = B*S*RH;
    qks_kernel<<<(nq + 255)/256, 256, 0, stream>>>(q, ksf, qks, nq);
    dim3 gdl(1, (B*S)/64);
    gemm_bias<false><<<gdl, 256, 0, stream>>>(qks, Wdk, bdk, dynlog, B*S, KNH, RH, KNH);
    dyn_conv<<<(nq + 255)/256, 256, 0, stream>>>(dynlog, v, dynout);
    gemm_bias<false><<<g64, 256, 0, stream>>>(dynout, Wda, bda, out1 + OUTHALF, B*S, OUTHALF, RH, HID);
}

// Round 3
// 323.019 us; speedup vs baseline: 5.7227x; 2.4649x over previous
//
#include <hip/hip_runtime.h>
#include <math.h>

#define B 8
#define S 1024
#define HID 768
#define RH 384
#define NH 6
#define HD 64
#define KW 9
#define KNH 54
#define OUTHALF 384
#define QLD 1152   // row stride of fused qkv buffer

typedef __attribute__((ext_vector_type(8))) short short8;
typedef __attribute__((ext_vector_type(4))) float f32x4;

// element-index XOR swizzle for [R][64] ushort LDS tiles (8-elem groups)
#define SWZ(r, c) (((r) << 6) + ((c) ^ (((r) & 7) << 3)))

__device__ __forceinline__ ushort f2bf(float x) {
    unsigned u = __float_as_uint(x);
    u += 0x7FFF + ((u >> 16) & 1);
    return (ushort)(u >> 16);
}
__device__ __forceinline__ float bf2f(ushort u) {
    return __uint_as_float(((unsigned)u) << 16);
}
__device__ __forceinline__ short8 cvt8(const float* p) {
    short8 r;
    #pragma unroll
    for (int i = 0; i < 8; i++) r[i] = (short)f2bf(p[i]);
    return r;
}

// ---------------- f32 -> bf16 bulk convert (8 elems/thread) ----------------
__global__ __launch_bounds__(256) void cvt_bf16(const float* __restrict__ in,
                                                ushort* __restrict__ out, int n8)
{
    int i = blockIdx.x*256 + threadIdx.x;
    if (i >= n8) return;
    float buf[8];
    *(float4*)&buf[0] = *(const float4*)(in + i*8);
    *(float4*)&buf[4] = *(const float4*)(in + i*8 + 4);
    *(short8*)(out + i*8) = cvt8(buf);
}

// ---------------- weight prep: bf16 transposed weights + fused qkv bias ----------------
__global__ __launch_bounds__(256) void prep_weights(
    const float* __restrict__ Wq, const float* __restrict__ Wk, const float* __restrict__ Wv,
    const float* __restrict__ bq, const float* __restrict__ bk, const float* __restrict__ bv,
    const float* __restrict__ pw_w, const float* __restrict__ Wsa,
    const float* __restrict__ Wda, const float* __restrict__ Wdk,
    ushort* __restrict__ WqkvT, ushort* __restrict__ pw_bf,
    ushort* __restrict__ WsaT, ushort* __restrict__ WdaT, ushort* __restrict__ WdkT,
    float* __restrict__ bqkv)
{
    int i = blockIdx.x*256 + threadIdx.x;
    if (i < 884736) {                          // WqkvT [1152][768]
        int n = i / 768, kk = i % 768;
        int w = n / 384, nn = n % 384;
        const float* W = (w == 0) ? Wq : (w == 1) ? Wk : Wv;
        WqkvT[i] = f2bf(W[kk*384 + nn]);
        return;
    }
    i -= 884736;
    if (i < 294912) { pw_bf[i] = f2bf(pw_w[i]); return; }   // [384][768] already [N][K]
    i -= 294912;
    if (i < 147456) {                          // WsaT [384][384]
        int n = i / 384, kk = i % 384;
        WsaT[i] = f2bf(Wsa[kk*384 + n]);
        return;
    }
    i -= 147456;
    if (i < 147456) {                          // WdaT [384][384]
        int n = i / 384, kk = i % 384;
        WdaT[i] = f2bf(Wda[kk*384 + n]);
        return;
    }
    i -= 147456;
    if (i < 49152) {                           // WdkT [128][384], rows >=54 zero
        int n = i / 384, kk = i % 384;
        WdkT[i] = (n < KNH) ? f2bf(Wdk[kk*KNH + n]) : (ushort)0;
        return;
    }
    i -= 49152;
    if (i < 1152) {                            // bqkv
        bqkv[i] = (i < 384) ? bq[i] : (i < 768) ? bk[i-384] : bv[i-768];
    }
}

// ---------------- bf16 MFMA GEMM: C = A @ Bt^T + bias ----------------
// A [M,Kd] bf16 row-major, Bt [Nt,Kd] bf16 (Nt = padded N, tiles full), Kd % 32 == 0.
// 128x128 tile, 4 waves each 64x64. OUTBF: write bf16, else f32.
template<bool OUTBF>
__global__ __launch_bounds__(256) void gemm_mfma(
    const ushort* __restrict__ A, const ushort* __restrict__ Bt,
    const float* __restrict__ bias, void* __restrict__ Cout,
    int N, int Kd, int ldc)
{
    __shared__ __attribute__((aligned(16))) ushort As[128*32];
    __shared__ __attribute__((aligned(16))) ushort Bs[128*32];
    const int t = threadIdx.x;
    const int wave = t >> 6, lane = t & 63;
    const int lr = lane & 15, lg = lane >> 4;
    const int wr = wave >> 1, wc = wave & 1;
    const int bm = blockIdx.y * 128, bn = blockIdx.x * 128;

    f32x4 acc[4][4] = {};
    const int srow = t >> 1, sseg = t & 1;
    const ushort* Arow = A + (size_t)(bm + srow)*Kd + sseg*16;
    const ushort* Brow = Bt + (size_t)(bn + srow)*Kd + sseg*16;
    const int g0 = (sseg*2) ^ (srow & 3), g1 = (sseg*2 + 1) ^ (srow & 3);
    const int swz = lg ^ (lr & 3);

    for (int k0 = 0; k0 < Kd; k0 += 32) {
        short8 av0 = *(const short8*)(Arow + k0);
        short8 av1 = *(const short8*)(Arow + k0 + 8);
        short8 bv0 = *(const short8*)(Brow + k0);
        short8 bv1 = *(const short8*)(Brow + k0 + 8);
        __syncthreads();
        *(short8*)&As[srow*32 + g0*8] = av0;
        *(short8*)&As[srow*32 + g1*8] = av1;
        *(short8*)&Bs[srow*32 + g0*8] = bv0;
        *(short8*)&Bs[srow*32 + g1*8] = bv1;
        __syncthreads();
        short8 af[4], bfr[4];
        #pragma unroll
        for (int m = 0; m < 4; m++)
            af[m] = *(const short8*)&As[(wr*64 + m*16 + lr)*32 + swz*8];
        #pragma unroll
        for (int n = 0; n < 4; n++)
            bfr[n] = *(const short8*)&Bs[(wc*64 + n*16 + lr)*32 + swz*8];
        #pragma unroll
        for (int m = 0; m < 4; m++)
            #pragma unroll
            for (int n = 0; n < 4; n++)
                acc[m][n] = __builtin_amdgcn_mfma_f32_16x16x32_bf16(af[m], bfr[n], acc[m][n], 0, 0, 0);
    }

    #pragma unroll
    for (int m = 0; m < 4; m++) {
        #pragma unroll
        for (int n = 0; n < 4; n++) {
            int gcol = bn + wc*64 + n*16 + lr;
            if (gcol >= N) continue;
            float bz = bias[gcol];
            #pragma unroll
            for (int r = 0; r < 4; r++) {
                size_t grow = bm + wr*64 + m*16 + lg*4 + r;
                float val = acc[m][n][r] + bz;
                if (OUTBF) ((ushort*)Cout)[grow*ldc + gcol] = f2bf(val);
                else       ((float*)Cout)[grow*ldc + gcol] = val;
            }
        }
    }
}

// ---------------- fused attention (bf16 qkv input) ----------------
__global__ __launch_bounds__(256) void attn_fused(
    const ushort* __restrict__ qkv, const int* __restrict__ mask,
    float* __restrict__ out0, ushort* __restrict__ attnws)
{
    __shared__ __attribute__((aligned(16))) ushort Ks[64*64];
    __shared__ __attribute__((aligned(16))) ushort Vt[64*64];
    __shared__ __attribute__((aligned(16))) ushort Ps[4][16*64];

    const int b = blockIdx.z, h = blockIdx.y, q0 = blockIdx.x * 64;
    const int t = threadIdx.x;
    const int wave = t >> 6, lane = t & 63;
    const int lr = lane & 15, lg = lane >> 4;

    const ushort* qrow = qkv + (size_t)(b*S + q0 + wave*16 + lr)*QLD + h*HD;
    short8 aQ0 = *(const short8*)(qrow + lg*8);
    short8 aQ1 = *(const short8*)(qrow + 32 + lg*8);

    const int srow = t >> 2;
    const int sseg = t & 3;
    const int* mrow = mask + b*S;
    const ushort* kbase = qkv + RH;
    const ushort* vbase = qkv + 2*RH;

    float lsum[4] = {0.f, 0.f, 0.f, 0.f};

    // ---------------- pass A: softmax denominators ----------------
    for (int kc = 0; kc < S; kc += 64) {
        const ushort* kr = kbase + (size_t)(b*S + kc + srow)*QLD + h*HD + sseg*16;
        short8 kv0 = *(const short8*)(kr);
        short8 kv1 = *(const short8*)(kr + 8);
        __syncthreads();
        *(short8*)&Ks[SWZ(srow, sseg*16)]     = kv0;
        *(short8*)&Ks[SWZ(srow, sseg*16 + 8)] = kv1;
        __syncthreads();
        #pragma unroll
        for (int t4 = 0; t4 < 4; t4++) {
            short8 b0 = *(const short8*)&Ks[SWZ(t4*16 + lr, lg*8)];
            short8 b1 = *(const short8*)&Ks[SWZ(t4*16 + lr, 32 + lg*8)];
            f32x4 c = {0.f, 0.f, 0.f, 0.f};
            c = __builtin_amdgcn_mfma_f32_16x16x32_bf16(aQ0, b0, c, 0, 0, 0);
            c = __builtin_amdgcn_mfma_f32_16x16x32_bf16(aQ1, b1, c, 0, 0, 0);
            float add = mrow[kc + t4*16 + lr] ? 0.f : -1e30f;
            #pragma unroll
            for (int r = 0; r < 4; r++)
                lsum[r] += __expf(c[r]*0.125f + add);
        }
    }
    #pragma unroll
    for (int r = 0; r < 4; r++) {
        #pragma unroll
        for (int off = 1; off < 16; off <<= 1)
            lsum[r] += __shfl_xor(lsum[r], off, 16);
    }
    float inv[4];
    #pragma unroll
    for (int r = 0; r < 4; r++) inv[r] = 1.f / lsum[r];

    // ---------------- pass B: recompute, normalize, write P, PV ----------------
    f32x4 o[4] = {};
    ushort* Psw = &Ps[wave][0];
    const size_t obase = ((size_t)((b*NH + h)*S) + q0 + wave*16) * (size_t)S;

    for (int kc = 0; kc < S; kc += 64) {
        const ushort* kr = kbase + (size_t)(b*S + kc + srow)*QLD + h*HD + sseg*16;
        short8 kv0 = *(const short8*)(kr);
        short8 kv1 = *(const short8*)(kr + 8);
        ushort vb[16];
        #pragma unroll
        for (int i = 0; i < 16; i++)
            vb[i] = vbase[(size_t)(b*S + kc + sseg*16 + i)*QLD + h*HD + srow];
        __syncthreads();
        *(short8*)&Ks[SWZ(srow, sseg*16)]     = kv0;
        *(short8*)&Ks[SWZ(srow, sseg*16 + 8)] = kv1;
        *(short8*)&Vt[SWZ(srow, sseg*16)]     = *(short8*)&vb[0];
        *(short8*)&Vt[SWZ(srow, sseg*16 + 8)] = *(short8*)&vb[8];
        __syncthreads();

        #pragma unroll
        for (int t4 = 0; t4 < 4; t4++) {
            short8 b0 = *(const short8*)&Ks[SWZ(t4*16 + lr, lg*8)];
            short8 b1 = *(const short8*)&Ks[SWZ(t4*16 + lr, 32 + lg*8)];
            f32x4 c = {0.f, 0.f, 0.f, 0.f};
            c = __builtin_amdgcn_mfma_f32_16x16x32_bf16(aQ0, b0, c, 0, 0, 0);
            c = __builtin_amdgcn_mfma_f32_16x16x32_bf16(aQ1, b1, c, 0, 0, 0);
            float add = mrow[kc + t4*16 + lr] ? 0.f : -1e30f;
            #pragma unroll
            for (int r = 0; r < 4; r++) {
                float p = __expf(c[r]*0.125f + add) * inv[r];
                out0[obase + (size_t)(lg*4 + r)*S + kc + t4*16 + lr] = p;
                Psw[SWZ(lg*4 + r, t4*16 + lr)] = f2bf(p);
            }
        }
        #pragma unroll
        for (int kh = 0; kh < 2; kh++) {
            short8 pa = *(const short8*)&Psw[SWZ(lr, kh*32 + lg*8)];
            #pragma unroll
            for (int dt = 0; dt < 4; dt++) {
                short8 vv = *(const short8*)&Vt[SWZ(dt*16 + lr, kh*32 + lg*8)];
                o[dt] = __builtin_amdgcn_mfma_f32_16x16x32_bf16(pa, vv, o[dt], 0, 0, 0);
            }
        }
    }

    #pragma unroll
    for (int dt = 0; dt < 4; dt++)
        #pragma unroll
        for (int r = 0; r < 4; r++)
            attnws[(size_t)(b*S + q0 + wave*16 + lg*4 + r)*RH + h*HD + dt*16 + lr] = f2bf(o[dt][r]);
}

// ---------------- depthwise conv (f32 in, bf16 out, 4 channels/thread) ----------------
__global__ __launch_bounds__(256) void dwconv_kernel(
    const float* __restrict__ key, const float* __restrict__ dw_w,
    const float* __restrict__ dw_b, ushort* __restrict__ dwout)
{
    int idx = blockIdx.x*256 + threadIdx.x;
    if (idx >= B*S*(HID/4)) return;
    int h4 = (idx % (HID/4))*4;
    int s  = (idx / (HID/4)) % S;
    int b  = idx / ((HID/4)*S);
    float4 acc = *(const float4*)(dw_b + h4);
    #pragma unroll
    for (int kk = 0; kk < KW; kk++) {
        int sp = s + kk - KW/2;
        if (sp >= 0 && sp < S) {
            float4 kv = *(const float4*)(key + ((size_t)b*S + sp)*HID + h4);
            acc.x += kv.x * dw_w[(h4+0)*KW + kk];
            acc.y += kv.y * dw_w[(h4+1)*KW + kk];
            acc.z += kv.z * dw_w[(h4+2)*KW + kk];
            acc.w += kv.w * dw_w[(h4+3)*KW + kk];
        }
    }
    ushort4 o;
    o.x = f2bf(acc.x); o.y = f2bf(acc.y); o.z = f2bf(acc.z); o.w = f2bf(acc.w);
    *(ushort4*)(dwout + ((size_t)b*S + s)*HID + h4) = o;
}

// ---------------- qks = q * ks_feat (bf16 q, f32 ksf -> bf16), 8/thread ----------------
__global__ __launch_bounds__(256) void qks_kernel(
    const ushort* __restrict__ qkv, const float* __restrict__ ksf,
    ushort* __restrict__ outb)
{
    int i = blockIdx.x*256 + threadIdx.x;
    if (i >= B*S*(RH/8)) return;
    int row = i / (RH/8);
    int c0 = (i % (RH/8))*8;
    short8 qv = *(const short8*)(qkv + (size_t)row*QLD + c0);
    float kf[8];
    *(float4*)&kf[0] = *(const float4*)(ksf + (size_t)row*RH + c0);
    *(float4*)&kf[4] = *(const float4*)(ksf + (size_t)row*RH + c0 + 4);
    short8 o;
    #pragma unroll
    for (int j = 0; j < 8; j++)
        o[j] = (short)f2bf(bf2f((ushort)qv[j]) * kf[j]);
    *(short8*)(outb + (size_t)row*RH + c0) = o;
}

// ---------------- dynamic conv: softmax over 9 taps + conv of v (4 ch/thread) ----------------
__global__ __launch_bounds__(256) void dyn_conv(
    const float* __restrict__ logits, const ushort* __restrict__ qkv,
    ushort* __restrict__ dynout)
{
    int idx = blockIdx.x*256 + threadIdx.x;
    if (idx >= B*S*(RH/4)) return;
    int r4 = (idx % (RH/4))*4;
    int s  = (idx / (RH/4)) % S;
    int b  = idx / ((RH/4)*S);
    int h  = r4 / HD;
    const float* lg = logits + ((size_t)b*S + s)*KNH + h*KW;
    float mx = lg[0];
    #pragma unroll
    for (int kk = 1; kk < KW; kk++) mx = fmaxf(mx, lg[kk]);
    float e[KW], sum = 0.f;
    #pragma unroll
    for (int kk = 0; kk < KW; kk++) { e[kk] = __expf(lg[kk]-mx); sum += e[kk]; }
    float inv = 1.f/sum;
    float acc[4] = {0.f, 0.f, 0.f, 0.f};
    const ushort* vbase = qkv + 2*RH;
    #pragma unroll
    for (int kk = 0; kk < KW; kk++) {
        int sp = s + kk - KW/2;
        if (sp >= 0 && sp < S) {
            const ushort* vp = vbase + (size_t)(b*S + sp)*QLD + r4;
            #pragma unroll
            for (int j = 0; j < 4; j++) acc[j] += bf2f(vp[j]) * e[kk];
        }
    }
    ushort4 o;
    o.x = f2bf(acc[0]*inv); o.y = f2bf(acc[1]*inv);
    o.z = f2bf(acc[2]*inv); o.w = f2bf(acc[3]*inv);
    *(ushort4*)(dynout + ((size_t)b*S + s)*RH + r4) = o;
}

extern "C" void kernel_launch(void* const* d_in, const int* in_sizes, int n_in,
                              void* d_out, int out_size, void* d_ws, size_t ws_size,
                              hipStream_t stream) {
    const float* query = (const float*)d_in[0];
    const int*   mask  = (const int*)d_in[1];
    const float* Wq    = (const float*)d_in[2];
    const float* bq    = (const float*)d_in[3];
    const float* Wk    = (const float*)d_in[4];
    const float* bk    = (const float*)d_in[5];
    const float* Wv    = (const float*)d_in[6];
    const float* bv    = (const float*)d_in[7];
    const float* dw_w  = (const float*)d_in[8];
    const float* dw_b  = (const float*)d_in[9];
    const float* pw_w  = (const float*)d_in[10];
    const float* pw_b  = (const float*)d_in[11];
    const float* Wsa   = (const float*)d_in[12];
    const float* bsa   = (const float*)d_in[13];
    const float* Wdk   = (const float*)d_in[14];
    const float* bdk   = (const float*)d_in[15];
    const float* Wda   = (const float*)d_in[16];
    const float* bda   = (const float*)d_in[17];

    float* out0 = (float*)d_out;                 // attn_wts [B,NH,S,S]
    float* out1 = out0 + (size_t)B*NH*S*S;       // concat [B,S,HID]

    char* wsb = (char*)d_ws;
    size_t off = 0;
    auto alloc = [&](size_t bytes) { char* p = wsb + off; off += (bytes + 255) & ~255ull; return p; };
    ushort* Xbf    = (ushort*)alloc((size_t)B*S*HID*2);
    ushort* qkvbf  = (ushort*)alloc((size_t)B*S*QLD*2);
    ushort* dwbf   = (ushort*)alloc((size_t)B*S*HID*2);
    float*  ksf    = (float*) alloc((size_t)B*S*RH*4);
    ushort* attnbf = (ushort*)alloc((size_t)B*S*RH*2);
    ushort* qksbf  = (ushort*)alloc((size_t)B*S*RH*2);
    ushort* dynbf  = (ushort*)alloc((size_t)B*S*RH*2);
    float*  dynlog = (float*) alloc((size_t)B*S*KNH*4);
    ushort* WqkvT  = (ushort*)alloc((size_t)QLD*HID*2);
    ushort* pw_bf  = (ushort*)alloc((size_t)RH*HID*2);
    ushort* WsaT   = (ushort*)alloc((size_t)RH*RH*2);
    ushort* WdaT   = (ushort*)alloc((size_t)RH*RH*2);
    ushort* WdkT   = (ushort*)alloc((size_t)128*RH*2);
    float*  bqkv   = (float*) alloc((size_t)QLD*4);

    const int M = B*S;  // 8192

    cvt_bf16<<<(M*HID/8 + 255)/256, 256, 0, stream>>>(query, Xbf, M*HID/8);
    prep_weights<<<(1524864 + 255)/256, 256, 0, stream>>>(
        Wq, Wk, Wv, bq, bk, bv, pw_w, Wsa, Wda, Wdk,
        WqkvT, pw_bf, WsaT, WdaT, WdkT, bqkv);

    // fused qkv projection -> bf16 [M, 1152]
    gemm_mfma<true><<<dim3(QLD/128, M/128), 256, 0, stream>>>(
        Xbf, WqkvT, bqkv, qkvbf, QLD, HID, QLD);

    // depthwise conv + pointwise GEMM
    dwconv_kernel<<<(M*(HID/4) + 255)/256, 256, 0, stream>>>(query, dw_w, dw_b, dwbf);
    gemm_mfma<false><<<dim3(RH/128, M/128), 256, 0, stream>>>(
        dwbf, pw_bf, pw_b, ksf, RH, HID, RH);

    // fused MFMA attention
    attn_fused<<<dim3(S/64, NH, B), 256, 0, stream>>>(qkvbf, mask, out0, attnbf);

    // self-attn output projection -> out1[:, :384]
    gemm_mfma<false><<<dim3(RH/128, M/128), 256, 0, stream>>>(
        attnbf, WsaT, bsa, out1, OUTHALF, RH, HID);

    // dynamic branch
    qks_kernel<<<(M*(RH/8) + 255)/256, 256, 0, stream>>>(qkvbf, ksf, qksbf);
    gemm_mfma<false><<<dim3(1, M/128), 256, 0, stream>>>(
        qksbf, WdkT, bdk, dynlog, KNH, RH, KNH);
    dyn_conv<<<(M*(RH/4) + 255)/256, 256, 0, stream>>>(dynlog, qkvbf, dynbf);
    gemm_mfma<false><<<dim3(RH/128, M/128), 256, 0, stream>>>(
        dynbf, WdaT, bda, out1 + OUTHALF, OUTHALF, RH, HID);
}

// Round 4
// 310.898 us; speedup vs baseline: 5.9458x; 1.0390x over previous
//
#include <hip/hip_runtime.h>
#include <math.h>

#define B 8
#define S 1024
#define HID 768
#define RH 384
#define NH 6
#define HD 64
#define KW 9
#define KNH 54
#define OUTHALF 384
#define QLD 1152   // row stride of fused qkv buffer
#define EXPSCALE 0.18033688f   // 0.125 * log2(e)

typedef __attribute__((ext_vector_type(8))) short short8;
typedef __attribute__((ext_vector_type(4))) float f32x4;

// element-index XOR swizzle for [R][64] ushort LDS tiles (8-elem groups)
#define SWZ(r, c) (((r) << 6) + ((c) ^ (((r) & 7) << 3)))

__device__ __forceinline__ ushort f2bf(float x) {
    unsigned u = __float_as_uint(x);
    u += 0x7FFF + ((u >> 16) & 1);
    return (ushort)(u >> 16);
}
__device__ __forceinline__ float bf2f(ushort u) {
    return __uint_as_float(((unsigned)u) << 16);
}
__device__ __forceinline__ short8 cvt8(const float* p) {
    short8 r;
    #pragma unroll
    for (int i = 0; i < 8; i++) r[i] = (short)f2bf(p[i]);
    return r;
}

// ---------------- fused f32->bf16 convert + depthwise conv (8 ch/thread) ----------------
__global__ __launch_bounds__(256) void cvt_dw_fused(
    const float* __restrict__ query, const float* __restrict__ dw_w,
    const float* __restrict__ dw_b, ushort* __restrict__ Xbf,
    ushort* __restrict__ dwout)
{
    int idx = blockIdx.x*256 + threadIdx.x;
    if (idx >= B*S*(HID/8)) return;
    int c0 = (idx % (HID/8))*8;
    int s  = (idx / (HID/8)) % S;
    int b  = idx / ((HID/8)*S);

    float ctr[8];
    *(float4*)&ctr[0] = *(const float4*)(query + ((size_t)b*S + s)*HID + c0);
    *(float4*)&ctr[4] = *(const float4*)(query + ((size_t)b*S + s)*HID + c0 + 4);
    *(short8*)(Xbf + ((size_t)b*S + s)*HID + c0) = cvt8(ctr);

    float acc[8];
    *(float4*)&acc[0] = *(const float4*)(dw_b + c0);
    *(float4*)&acc[4] = *(const float4*)(dw_b + c0 + 4);
    #pragma unroll
    for (int kk = 0; kk < KW; kk++) {
        int sp = s + kk - KW/2;
        if (sp >= 0 && sp < S) {
            float row[8];
            *(float4*)&row[0] = *(const float4*)(query + ((size_t)b*S + sp)*HID + c0);
            *(float4*)&row[4] = *(const float4*)(query + ((size_t)b*S + sp)*HID + c0 + 4);
            #pragma unroll
            for (int j = 0; j < 8; j++)
                acc[j] += row[j] * dw_w[(c0+j)*KW + kk];
        }
    }
    *(short8*)(dwout + ((size_t)b*S + s)*HID + c0) = cvt8(acc);
}

// ---------------- weight prep: bf16 transposed weights + fused qkv bias ----------------
__global__ __launch_bounds__(256) void prep_weights(
    const float* __restrict__ Wq, const float* __restrict__ Wk, const float* __restrict__ Wv,
    const float* __restrict__ bq, const float* __restrict__ bk, const float* __restrict__ bv,
    const float* __restrict__ pw_w, const float* __restrict__ Wsa,
    const float* __restrict__ Wda, const float* __restrict__ Wdk,
    ushort* __restrict__ WqkvT, ushort* __restrict__ pw_bf,
    ushort* __restrict__ WsaT, ushort* __restrict__ WdaT, ushort* __restrict__ WdkT,
    float* __restrict__ bqkv)
{
    int i = blockIdx.x*256 + threadIdx.x;
    if (i < 884736) {                          // WqkvT [1152][768]
        int n = i / 768, kk = i % 768;
        int w = n / 384, nn = n % 384;
        const float* W = (w == 0) ? Wq : (w == 1) ? Wk : Wv;
        WqkvT[i] = f2bf(W[kk*384 + nn]);
        return;
    }
    i -= 884736;
    if (i < 294912) { pw_bf[i] = f2bf(pw_w[i]); return; }   // [384][768] already [N][K]
    i -= 294912;
    if (i < 147456) {                          // WsaT [384][384]
        int n = i / 384, kk = i % 384;
        WsaT[i] = f2bf(Wsa[kk*384 + n]);
        return;
    }
    i -= 147456;
    if (i < 147456) {                          // WdaT [384][384]
        int n = i / 384, kk = i % 384;
        WdaT[i] = f2bf(Wda[kk*384 + n]);
        return;
    }
    i -= 147456;
    if (i < 49152) {                           // WdkT [128][384], rows >=54 zero
        int n = i / 384, kk = i % 384;
        WdkT[i] = (n < KNH) ? f2bf(Wdk[kk*KNH + n]) : (ushort)0;
        return;
    }
    i -= 49152;
    if (i < 1152) {                            // bqkv
        bqkv[i] = (i < 384) ? bq[i] : (i < 768) ? bk[i-384] : bv[i-768];
    }
}

// ---------------- bf16 MFMA GEMM, 128x128 tile: C = A @ Bt^T + bias ----------------
template<bool OUTBF>
__global__ __launch_bounds__(256) void gemm_mfma(
    const ushort* __restrict__ A, const ushort* __restrict__ Bt,
    const float* __restrict__ bias, void* __restrict__ Cout,
    int N, int Kd, int ldc)
{
    __shared__ __attribute__((aligned(16))) ushort As[128*32];
    __shared__ __attribute__((aligned(16))) ushort Bs[128*32];
    const int t = threadIdx.x;
    const int wave = t >> 6, lane = t & 63;
    const int lr = lane & 15, lg = lane >> 4;
    const int wr = wave >> 1, wc = wave & 1;
    const int bm = blockIdx.y * 128, bn = blockIdx.x * 128;

    f32x4 acc[4][4] = {};
    const int srow = t >> 1, sseg = t & 1;
    const ushort* Arow = A + (size_t)(bm + srow)*Kd + sseg*16;
    const ushort* Brow = Bt + (size_t)(bn + srow)*Kd + sseg*16;
    const int g0 = (sseg*2) ^ (srow & 3), g1 = (sseg*2 + 1) ^ (srow & 3);
    const int swz = lg ^ (lr & 3);

    for (int k0 = 0; k0 < Kd; k0 += 32) {
        short8 av0 = *(const short8*)(Arow + k0);
        short8 av1 = *(const short8*)(Arow + k0 + 8);
        short8 bv0 = *(const short8*)(Brow + k0);
        short8 bv1 = *(const short8*)(Brow + k0 + 8);
        __syncthreads();
        *(short8*)&As[srow*32 + g0*8] = av0;
        *(short8*)&As[srow*32 + g1*8] = av1;
        *(short8*)&Bs[srow*32 + g0*8] = bv0;
        *(short8*)&Bs[srow*32 + g1*8] = bv1;
        __syncthreads();
        short8 af[4], bfr[4];
        #pragma unroll
        for (int m = 0; m < 4; m++)
            af[m] = *(const short8*)&As[(wr*64 + m*16 + lr)*32 + swz*8];
        #pragma unroll
        for (int n = 0; n < 4; n++)
            bfr[n] = *(const short8*)&Bs[(wc*64 + n*16 + lr)*32 + swz*8];
        #pragma unroll
        for (int m = 0; m < 4; m++)
            #pragma unroll
            for (int n = 0; n < 4; n++)
                acc[m][n] = __builtin_amdgcn_mfma_f32_16x16x32_bf16(af[m], bfr[n], acc[m][n], 0, 0, 0);
    }

    #pragma unroll
    for (int m = 0; m < 4; m++) {
        #pragma unroll
        for (int n = 0; n < 4; n++) {
            int gcol = bn + wc*64 + n*16 + lr;
            if (gcol >= N) continue;
            float bz = bias[gcol];
            #pragma unroll
            for (int r = 0; r < 4; r++) {
                size_t grow = bm + wr*64 + m*16 + lg*4 + r;
                float val = acc[m][n][r] + bz;
                if (OUTBF) ((ushort*)Cout)[grow*ldc + gcol] = f2bf(val);
                else       ((float*)Cout)[grow*ldc + gcol] = val;
            }
        }
    }
}

// ---------------- bf16 MFMA GEMM, 64x64 tile (high occupancy for small N) ----------------
// DUAL: blockIdx.z selects branch (0: A0/Bt0/bias0 -> C, 1: A1/Bt1/bias1 -> C+OUTHALF)
template<bool OUTBF, bool DUAL>
__global__ __launch_bounds__(256) void gemm64(
    const ushort* __restrict__ A0, const ushort* __restrict__ Bt0,
    const float* __restrict__ bias0, void* __restrict__ C0,
    const ushort* __restrict__ A1, const ushort* __restrict__ Bt1,
    const float* __restrict__ bias1,
    int N, int Kd, int ldc)
{
    __shared__ __attribute__((aligned(16))) ushort As[64*32];
    __shared__ __attribute__((aligned(16))) ushort Bs[64*32];
    const ushort* A  = (DUAL && blockIdx.z) ? A1 : A0;
    const ushort* Bt = (DUAL && blockIdx.z) ? Bt1 : Bt0;
    const float* bias = (DUAL && blockIdx.z) ? bias1 : bias0;
    const int coff = (DUAL && blockIdx.z) ? OUTHALF : 0;

    const int t = threadIdx.x;
    const int wave = t >> 6, lane = t & 63;
    const int lr = lane & 15, lg = lane >> 4;
    const int wr = wave >> 1, wc = wave & 1;
    const int bm = blockIdx.y * 64, bn = blockIdx.x * 64;

    f32x4 acc[2][2] = {};
    const int srow = t >> 2, sseg = t & 3;
    const ushort* Arow = A + (size_t)(bm + srow)*Kd + sseg*8;
    const ushort* Brow = Bt + (size_t)(bn + srow)*Kd + sseg*8;
    const int gs = sseg ^ (srow & 3);
    const int swz = lg ^ (lr & 3);

    for (int k0 = 0; k0 < Kd; k0 += 32) {
        short8 av = *(const short8*)(Arow + k0);
        short8 bv = *(const short8*)(Brow + k0);
        __syncthreads();
        *(short8*)&As[srow*32 + gs*8] = av;
        *(short8*)&Bs[srow*32 + gs*8] = bv;
        __syncthreads();
        short8 af[2], bfr[2];
        #pragma unroll
        for (int m = 0; m < 2; m++)
            af[m] = *(const short8*)&As[(wr*32 + m*16 + lr)*32 + swz*8];
        #pragma unroll
        for (int n = 0; n < 2; n++)
            bfr[n] = *(const short8*)&Bs[(wc*32 + n*16 + lr)*32 + swz*8];
        #pragma unroll
        for (int m = 0; m < 2; m++)
            #pragma unroll
            for (int n = 0; n < 2; n++)
                acc[m][n] = __builtin_amdgcn_mfma_f32_16x16x32_bf16(af[m], bfr[n], acc[m][n], 0, 0, 0);
    }

    #pragma unroll
    for (int m = 0; m < 2; m++) {
        #pragma unroll
        for (int n = 0; n < 2; n++) {
            int gcol = bn + wc*32 + n*16 + lr;
            if (gcol >= N) continue;
            float bz = bias[gcol];
            #pragma unroll
            for (int r = 0; r < 4; r++) {
                size_t grow = bm + wr*32 + m*16 + lg*4 + r;
                float val = acc[m][n][r] + bz;
                if (OUTBF) ((ushort*)C0)[grow*ldc + gcol + coff] = f2bf(val);
                else       ((float*)C0)[grow*ldc + gcol + coff] = val;
            }
        }
    }
}

// ---------------- fused qks + dynamic-kernel GEMM: dynlog = (q .* ksf) @ WdkT^T + bdk ----------------
// 64 threads (1 wave) per block, 16 rows. B-fragments straight from L2 (WdkT hot, 96 KB).
__global__ __launch_bounds__(64) void gemm_qksdk(
    const ushort* __restrict__ qkv, const float* __restrict__ ksf,
    const ushort* __restrict__ WdkT, const float* __restrict__ bdk,
    float* __restrict__ dynlog)
{
    const int lane = threadIdx.x;
    const int lr = lane & 15, lg = lane >> 4;
    const int r0 = blockIdx.x * 16;
    const int row = r0 + lr;

    f32x4 acc[4] = {};
    for (int ks = 0; ks < RH/32; ks++) {
        int k0 = ks*32 + lg*8;
        short8 qv = *(const short8*)(qkv + (size_t)row*QLD + k0);
        float kf[8];
        *(float4*)&kf[0] = *(const float4*)(ksf + (size_t)row*RH + k0);
        *(float4*)&kf[4] = *(const float4*)(ksf + (size_t)row*RH + k0 + 4);
        short8 afr;
        #pragma unroll
        for (int j = 0; j < 8; j++)
            afr[j] = (short)f2bf(bf2f((ushort)qv[j]) * kf[j]);
        #pragma unroll
        for (int t4 = 0; t4 < 4; t4++) {
            short8 bfr = *(const short8*)(WdkT + (size_t)(t4*16 + lr)*RH + k0);
            acc[t4] = __builtin_amdgcn_mfma_f32_16x16x32_bf16(afr, bfr, acc[t4], 0, 0, 0);
        }
    }
    #pragma unroll
    for (int t4 = 0; t4 < 4; t4++) {
        int n = t4*16 + lr;
        if (n >= KNH) continue;
        float bz = bdk[n];
        #pragma unroll
        for (int r = 0; r < 4; r++)
            dynlog[(size_t)(r0 + lg*4 + r)*KNH + n] = acc[t4][r] + bz;
    }
}

// ---------------- fused attention (bf16 qkv input) ----------------
__global__ __launch_bounds__(256) void attn_fused(
    const ushort* __restrict__ qkv, const int* __restrict__ mask,
    float* __restrict__ out0, ushort* __restrict__ attnws)
{
    __shared__ __attribute__((aligned(16))) ushort Ks[64*64];
    __shared__ __attribute__((aligned(16))) ushort Vt[64*64];
    __shared__ __attribute__((aligned(16))) ushort Ps[4][16*64];

    const int b = blockIdx.z, h = blockIdx.y, q0 = blockIdx.x * 64;
    const int t = threadIdx.x;
    const int wave = t >> 6, lane = t & 63;
    const int lr = lane & 15, lg = lane >> 4;

    const ushort* qrow = qkv + (size_t)(b*S + q0 + wave*16 + lr)*QLD + h*HD;
    short8 aQ0 = *(const short8*)(qrow + lg*8);
    short8 aQ1 = *(const short8*)(qrow + 32 + lg*8);

    const int srow = t >> 2;
    const int sseg = t & 3;
    const int* mrow = mask + b*S;
    const ushort* kbase = qkv + RH;
    const ushort* vbase = qkv + 2*RH;

    float lsum[4] = {0.f, 0.f, 0.f, 0.f};

    // ---------------- pass A: softmax denominators ----------------
    for (int kc = 0; kc < S; kc += 64) {
        const ushort* kr = kbase + (size_t)(b*S + kc + srow)*QLD + h*HD + sseg*16;
        short8 kv0 = *(const short8*)(kr);
        short8 kv1 = *(const short8*)(kr + 8);
        __syncthreads();
        *(short8*)&Ks[SWZ(srow, sseg*16)]     = kv0;
        *(short8*)&Ks[SWZ(srow, sseg*16 + 8)] = kv1;
        __syncthreads();
        #pragma unroll
        for (int t4 = 0; t4 < 4; t4++) {
            short8 b0 = *(const short8*)&Ks[SWZ(t4*16 + lr, lg*8)];
            short8 b1 = *(const short8*)&Ks[SWZ(t4*16 + lr, 32 + lg*8)];
            f32x4 c = {0.f, 0.f, 0.f, 0.f};
            c = __builtin_amdgcn_mfma_f32_16x16x32_bf16(aQ0, b0, c, 0, 0, 0);
            c = __builtin_amdgcn_mfma_f32_16x16x32_bf16(aQ1, b1, c, 0, 0, 0);
            float add = mrow[kc + t4*16 + lr] ? 0.f : -1e30f;
            #pragma unroll
            for (int r = 0; r < 4; r++)
                lsum[r] += exp2f(c[r]*EXPSCALE + add);
        }
    }
    #pragma unroll
    for (int r = 0; r < 4; r++) {
        #pragma unroll
        for (int off = 1; off < 16; off <<= 1)
            lsum[r] += __shfl_xor(lsum[r], off, 16);
    }
    float inv[4];
    #pragma unroll
    for (int r = 0; r < 4; r++) inv[r] = 1.f / lsum[r];

    // ---------------- pass B: recompute, normalize, write P, PV ----------------
    f32x4 o[4] = {};
    ushort* Psw = &Ps[wave][0];
    const size_t obase = ((size_t)((b*NH + h)*S) + q0 + wave*16) * (size_t)S;

    for (int kc = 0; kc < S; kc += 64) {
        const ushort* kr = kbase + (size_t)(b*S + kc + srow)*QLD + h*HD + sseg*16;
        short8 kv0 = *(const short8*)(kr);
        short8 kv1 = *(const short8*)(kr + 8);
        ushort vb[16];
        #pragma unroll
        for (int i = 0; i < 16; i++)
            vb[i] = vbase[(size_t)(b*S + kc + sseg*16 + i)*QLD + h*HD + srow];
        __syncthreads();
        *(short8*)&Ks[SWZ(srow, sseg*16)]     = kv0;
        *(short8*)&Ks[SWZ(srow, sseg*16 + 8)] = kv1;
        *(short8*)&Vt[SWZ(srow, sseg*16)]     = *(short8*)&vb[0];
        *(short8*)&Vt[SWZ(srow, sseg*16 + 8)] = *(short8*)&vb[8];
        __syncthreads();

        #pragma unroll
        for (int t4 = 0; t4 < 4; t4++) {
            short8 b0 = *(const short8*)&Ks[SWZ(t4*16 + lr, lg*8)];
            short8 b1 = *(const short8*)&Ks[SWZ(t4*16 + lr, 32 + lg*8)];
            f32x4 c = {0.f, 0.f, 0.f, 0.f};
            c = __builtin_amdgcn_mfma_f32_16x16x32_bf16(aQ0, b0, c, 0, 0, 0);
            c = __builtin_amdgcn_mfma_f32_16x16x32_bf16(aQ1, b1, c, 0, 0, 0);
            float add = mrow[kc + t4*16 + lr] ? 0.f : -1e30f;
            #pragma unroll
            for (int r = 0; r < 4; r++) {
                float p = exp2f(c[r]*EXPSCALE + add) * inv[r];
                out0[obase + (size_t)(lg*4 + r)*S + kc + t4*16 + lr] = p;
                Psw[SWZ(lg*4 + r, t4*16 + lr)] = f2bf(p);
            }
        }
        #pragma unroll
        for (int kh = 0; kh < 2; kh++) {
            short8 pa = *(const short8*)&Psw[SWZ(lr, kh*32 + lg*8)];
            #pragma unroll
            for (int dt = 0; dt < 4; dt++) {
                short8 vv = *(const short8*)&Vt[SWZ(dt*16 + lr, kh*32 + lg*8)];
                o[dt] = __builtin_amdgcn_mfma_f32_16x16x32_bf16(pa, vv, o[dt], 0, 0, 0);
            }
        }
    }

    #pragma unroll
    for (int dt = 0; dt < 4; dt++)
        #pragma unroll
        for (int r = 0; r < 4; r++)
            attnws[(size_t)(b*S + q0 + wave*16 + lg*4 + r)*RH + h*HD + dt*16 + lr] = f2bf(o[dt][r]);
}

// ---------------- dynamic conv: softmax over 9 taps + conv of v (4 ch/thread) ----------------
__global__ __launch_bounds__(256) void dyn_conv(
    const float* __restrict__ logits, const ushort* __restrict__ qkv,
    ushort* __restrict__ dynout)
{
    int idx = blockIdx.x*256 + threadIdx.x;
    if (idx >= B*S*(RH/4)) return;
    int r4 = (idx % (RH/4))*4;
    int s  = (idx / (RH/4)) % S;
    int b  = idx / ((RH/4)*S);
    int h  = r4 / HD;
    const float* lg = logits + ((size_t)b*S + s)*KNH + h*KW;
    float mx = lg[0];
    #pragma unroll
    for (int kk = 1; kk < KW; kk++) mx = fmaxf(mx, lg[kk]);
    float e[KW], sum = 0.f;
    #pragma unroll
    for (int kk = 0; kk < KW; kk++) { e[kk] = __expf(lg[kk]-mx); sum += e[kk]; }
    float inv = 1.f/sum;
    float acc[4] = {0.f, 0.f, 0.f, 0.f};
    const ushort* vbase = qkv + 2*RH;
    #pragma unroll
    for (int kk = 0; kk < KW; kk++) {
        int sp = s + kk - KW/2;
        if (sp >= 0 && sp < S) {
            const ushort* vp = vbase + (size_t)(b*S + sp)*QLD + r4;
            #pragma unroll
            for (int j = 0; j < 4; j++) acc[j] += bf2f(vp[j]) * e[kk];
        }
    }
    ushort4 o;
    o.x = f2bf(acc[0]*inv); o.y = f2bf(acc[1]*inv);
    o.z = f2bf(acc[2]*inv); o.w = f2bf(acc[3]*inv);
    *(ushort4*)(dynout + ((size_t)b*S + s)*RH + r4) = o;
}

extern "C" void kernel_launch(void* const* d_in, const int* in_sizes, int n_in,
                              void* d_out, int out_size, void* d_ws, size_t ws_size,
                              hipStream_t stream) {
    const float* query = (const float*)d_in[0];
    const int*   mask  = (const int*)d_in[1];
    const float* Wq    = (const float*)d_in[2];
    const float* bq    = (const float*)d_in[3];
    const float* Wk    = (const float*)d_in[4];
    const float* bk    = (const float*)d_in[5];
    const float* Wv    = (const float*)d_in[6];
    const float* bv    = (const float*)d_in[7];
    const float* dw_w  = (const float*)d_in[8];
    const float* dw_b  = (const float*)d_in[9];
    const float* pw_w  = (const float*)d_in[10];
    const float* pw_b  = (const float*)d_in[11];
    const float* Wsa   = (const float*)d_in[12];
    const float* bsa   = (const float*)d_in[13];
    const float* Wdk   = (const float*)d_in[14];
    const float* bdk   = (const float*)d_in[15];
    const float* Wda   = (const float*)d_in[16];
    const float* bda   = (const float*)d_in[17];

    float* out0 = (float*)d_out;                 // attn_wts [B,NH,S,S]
    float* out1 = out0 + (size_t)B*NH*S*S;       // concat [B,S,HID]

    char* wsb = (char*)d_ws;
    size_t off = 0;
    auto alloc = [&](size_t bytes) { char* p = wsb + off; off += (bytes + 255) & ~255ull; return p; };
    ushort* Xbf    = (ushort*)alloc((size_t)B*S*HID*2);
    ushort* qkvbf  = (ushort*)alloc((size_t)B*S*QLD*2);
    ushort* dwbf   = (ushort*)alloc((size_t)B*S*HID*2);
    float*  ksf    = (float*) alloc((size_t)B*S*RH*4);
    ushort* attnbf = (ushort*)alloc((size_t)B*S*RH*2);
    ushort* dynbf  = (ushort*)alloc((size_t)B*S*RH*2);
    float*  dynlog = (float*) alloc((size_t)B*S*KNH*4);
    ushort* WqkvT  = (ushort*)alloc((size_t)QLD*HID*2);
    ushort* pw_bf  = (ushort*)alloc((size_t)RH*HID*2);
    ushort* WsaT   = (ushort*)alloc((size_t)RH*RH*2);
    ushort* WdaT   = (ushort*)alloc((size_t)RH*RH*2);
    ushort* WdkT   = (ushort*)alloc((size_t)128*RH*2);
    float*  bqkv   = (float*) alloc((size_t)QLD*4);

    const int M = B*S;  // 8192

    prep_weights<<<(1524864 + 255)/256, 256, 0, stream>>>(
        Wq, Wk, Wv, bq, bk, bv, pw_w, Wsa, Wda, Wdk,
        WqkvT, pw_bf, WsaT, WdaT, WdkT, bqkv);

    // fused bf16 convert + depthwise conv
    cvt_dw_fused<<<(M*(HID/8) + 255)/256, 256, 0, stream>>>(query, dw_w, dw_b, Xbf, dwbf);

    // fused qkv projection -> bf16 [M, 1152]
    gemm_mfma<true><<<dim3(QLD/128, M/128), 256, 0, stream>>>(
        Xbf, WqkvT, bqkv, qkvbf, QLD, HID, QLD);

    // pointwise conv GEMM -> ksf f32
    gemm64<false, false><<<dim3(RH/64, M/64), 256, 0, stream>>>(
        dwbf, pw_bf, pw_b, ksf, nullptr, nullptr, nullptr, RH, HID, RH);

    // fused MFMA attention
    attn_fused<<<dim3(S/64, NH, B), 256, 0, stream>>>(qkvbf, mask, out0, attnbf);

    // fused qks + dynamic-kernel logits GEMM
    gemm_qksdk<<<M/16, 64, 0, stream>>>(qkvbf, ksf, WdkT, bdk, dynlog);

    // dynamic conv
    dyn_conv<<<(M*(RH/4) + 255)/256, 256, 0, stream>>>(dynlog, qkvbf, dynbf);

    // dual output projection: out1[:, :384] = attnbf@WsaT, out1[:, 384:] = dynbf@WdaT
    gemm64<false, true><<<dim3(OUTHALF/64, M/64, 2), 256, 0, stream>>>(
        attnbf, WsaT, bsa, out1, dynbf, WdaT, bda, OUTHALF, RH, HID);
}

// Round 5
// 303.548 us; speedup vs baseline: 6.0897x; 1.0242x over previous
//
#include <hip/hip_runtime.h>
#include <math.h>

#define B 8
#define S 1024
#define HID 768
#define RH 384
#define NH 6
#define HD 64
#define KW 9
#define KNH 54
#define OUTHALF 384
#define QLD 1152   // row stride of fused qkv buffer
#define EXPSCALE 0.18033688f   // 0.125 * log2(e)

typedef __attribute__((ext_vector_type(8))) short short8;
typedef __attribute__((ext_vector_type(4))) float f32x4;

// element-index XOR swizzle for [R][64] ushort LDS tiles (8-elem groups)
#define SWZ(r, c) (((r) << 6) + ((c) ^ (((r) & 7) << 3)))

__device__ __forceinline__ ushort f2bf(float x) {
    unsigned u = __float_as_uint(x);
    u += 0x7FFF + ((u >> 16) & 1);
    return (ushort)(u >> 16);
}
__device__ __forceinline__ float bf2f(ushort u) {
    return __uint_as_float(((unsigned)u) << 16);
}
__device__ __forceinline__ short8 cvt8(const float* p) {
    short8 r;
    #pragma unroll
    for (int i = 0; i < 8; i++) r[i] = (short)f2bf(p[i]);
    return r;
}

// ---------------- fused f32->bf16 convert + depthwise conv (8 ch/thread) ----------------
__global__ __launch_bounds__(256) void cvt_dw_fused(
    const float* __restrict__ query, const float* __restrict__ dw_w,
    const float* __restrict__ dw_b, ushort* __restrict__ Xbf,
    ushort* __restrict__ dwout)
{
    int idx = blockIdx.x*256 + threadIdx.x;
    if (idx >= B*S*(HID/8)) return;
    int c0 = (idx % (HID/8))*8;
    int s  = (idx / (HID/8)) % S;
    int b  = idx / ((HID/8)*S);

    float ctr[8];
    *(float4*)&ctr[0] = *(const float4*)(query + ((size_t)b*S + s)*HID + c0);
    *(float4*)&ctr[4] = *(const float4*)(query + ((size_t)b*S + s)*HID + c0 + 4);
    *(short8*)(Xbf + ((size_t)b*S + s)*HID + c0) = cvt8(ctr);

    float acc[8];
    *(float4*)&acc[0] = *(const float4*)(dw_b + c0);
    *(float4*)&acc[4] = *(const float4*)(dw_b + c0 + 4);
    #pragma unroll
    for (int kk = 0; kk < KW; kk++) {
        int sp = s + kk - KW/2;
        if (sp >= 0 && sp < S) {
            float row[8];
            *(float4*)&row[0] = *(const float4*)(query + ((size_t)b*S + sp)*HID + c0);
            *(float4*)&row[4] = *(const float4*)(query + ((size_t)b*S + sp)*HID + c0 + 4);
            #pragma unroll
            for (int j = 0; j < 8; j++)
                acc[j] += row[j] * dw_w[(c0+j)*KW + kk];
        }
    }
    *(short8*)(dwout + ((size_t)b*S + s)*HID + c0) = cvt8(acc);
}

// ---------------- weight prep: bf16 transposed weights + fused qkv bias ----------------
__global__ __launch_bounds__(256) void prep_weights(
    const float* __restrict__ Wq, const float* __restrict__ Wk, const float* __restrict__ Wv,
    const float* __restrict__ bq, const float* __restrict__ bk, const float* __restrict__ bv,
    const float* __restrict__ pw_w, const float* __restrict__ Wsa,
    const float* __restrict__ Wda, const float* __restrict__ Wdk,
    ushort* __restrict__ WqkvT, ushort* __restrict__ pw_bf,
    ushort* __restrict__ WsaT, ushort* __restrict__ WdaT, ushort* __restrict__ WdkT,
    float* __restrict__ bqkv)
{
    int i = blockIdx.x*256 + threadIdx.x;
    if (i < 884736) {                          // WqkvT [1152][768]
        int n = i / 768, kk = i % 768;
        int w = n / 384, nn = n % 384;
        const float* W = (w == 0) ? Wq : (w == 1) ? Wk : Wv;
        WqkvT[i] = f2bf(W[kk*384 + nn]);
        return;
    }
    i -= 884736;
    if (i < 294912) { pw_bf[i] = f2bf(pw_w[i]); return; }   // [384][768] already [N][K]
    i -= 294912;
    if (i < 147456) {                          // WsaT [384][384]
        int n = i / 384, kk = i % 384;
        WsaT[i] = f2bf(Wsa[kk*384 + n]);
        return;
    }
    i -= 147456;
    if (i < 147456) {                          // WdaT [384][384]
        int n = i / 384, kk = i % 384;
        WdaT[i] = f2bf(Wda[kk*384 + n]);
        return;
    }
    i -= 147456;
    if (i < 49152) {                           // WdkT [128][384], rows >=54 zero
        int n = i / 384, kk = i % 384;
        WdkT[i] = (n < KNH) ? f2bf(Wdk[kk*KNH + n]) : (ushort)0;
        return;
    }
    i -= 49152;
    if (i < 1152) {                            // bqkv
        bqkv[i] = (i < 384) ? bq[i] : (i < 768) ? bk[i-384] : bv[i-768];
    }
}

// ---------------- bf16 MFMA GEMM, 128x128 tile, prefetch-pipelined ----------------
template<bool OUTBF>
__global__ __launch_bounds__(256) void gemm_mfma(
    const ushort* __restrict__ A, const ushort* __restrict__ Bt,
    const float* __restrict__ bias, void* __restrict__ Cout,
    int N, int Kd, int ldc)
{
    __shared__ __attribute__((aligned(16))) ushort As[128*32];
    __shared__ __attribute__((aligned(16))) ushort Bs[128*32];
    const int t = threadIdx.x;
    const int wave = t >> 6, lane = t & 63;
    const int lr = lane & 15, lg = lane >> 4;
    const int wr = wave >> 1, wc = wave & 1;
    const int bm = blockIdx.y * 128, bn = blockIdx.x * 128;

    f32x4 acc[4][4] = {};
    const int srow = t >> 1, sseg = t & 1;
    const ushort* Arow = A + (size_t)(bm + srow)*Kd + sseg*16;
    const ushort* Brow = Bt + (size_t)(bn + srow)*Kd + sseg*16;
    const int g0 = (sseg*2) ^ (srow & 3), g1 = (sseg*2 + 1) ^ (srow & 3);
    const int swz = lg ^ (lr & 3);

    short8 av0 = *(const short8*)(Arow);
    short8 av1 = *(const short8*)(Arow + 8);
    short8 bv0 = *(const short8*)(Brow);
    short8 bv1 = *(const short8*)(Brow + 8);

    for (int k0 = 0; k0 < Kd; k0 += 32) {
        __syncthreads();
        *(short8*)&As[srow*32 + g0*8] = av0;
        *(short8*)&As[srow*32 + g1*8] = av1;
        *(short8*)&Bs[srow*32 + g0*8] = bv0;
        *(short8*)&Bs[srow*32 + g1*8] = bv1;
        __syncthreads();
        if (k0 + 32 < Kd) {       // issue next-tile loads early (overlap with MFMA)
            av0 = *(const short8*)(Arow + k0 + 32);
            av1 = *(const short8*)(Arow + k0 + 40);
            bv0 = *(const short8*)(Brow + k0 + 32);
            bv1 = *(const short8*)(Brow + k0 + 40);
        }
        short8 af[4], bfr[4];
        #pragma unroll
        for (int m = 0; m < 4; m++)
            af[m] = *(const short8*)&As[(wr*64 + m*16 + lr)*32 + swz*8];
        #pragma unroll
        for (int n = 0; n < 4; n++)
            bfr[n] = *(const short8*)&Bs[(wc*64 + n*16 + lr)*32 + swz*8];
        #pragma unroll
        for (int m = 0; m < 4; m++)
            #pragma unroll
            for (int n = 0; n < 4; n++)
                acc[m][n] = __builtin_amdgcn_mfma_f32_16x16x32_bf16(af[m], bfr[n], acc[m][n], 0, 0, 0);
    }

    #pragma unroll
    for (int m = 0; m < 4; m++) {
        #pragma unroll
        for (int n = 0; n < 4; n++) {
            int gcol = bn + wc*64 + n*16 + lr;
            if (gcol >= N) continue;
            float bz = bias[gcol];
            #pragma unroll
            for (int r = 0; r < 4; r++) {
                size_t grow = bm + wr*64 + m*16 + lg*4 + r;
                float val = acc[m][n][r] + bz;
                if (OUTBF) ((ushort*)Cout)[grow*ldc + gcol] = f2bf(val);
                else       ((float*)Cout)[grow*ldc + gcol] = val;
            }
        }
    }
}

// ---------------- bf16 MFMA GEMM, 64x64 tile, prefetch-pipelined ----------------
// DUAL: blockIdx.z selects branch (0: A0/Bt0/bias0 -> C, 1: A1/Bt1/bias1 -> C+OUTHALF)
template<bool OUTBF, bool DUAL>
__global__ __launch_bounds__(256) void gemm64(
    const ushort* __restrict__ A0, const ushort* __restrict__ Bt0,
    const float* __restrict__ bias0, void* __restrict__ C0,
    const ushort* __restrict__ A1, const ushort* __restrict__ Bt1,
    const float* __restrict__ bias1,
    int N, int Kd, int ldc)
{
    __shared__ __attribute__((aligned(16))) ushort As[64*32];
    __shared__ __attribute__((aligned(16))) ushort Bs[64*32];
    const ushort* A  = (DUAL && blockIdx.z) ? A1 : A0;
    const ushort* Bt = (DUAL && blockIdx.z) ? Bt1 : Bt0;
    const float* bias = (DUAL && blockIdx.z) ? bias1 : bias0;
    const int coff = (DUAL && blockIdx.z) ? OUTHALF : 0;

    const int t = threadIdx.x;
    const int wave = t >> 6, lane = t & 63;
    const int lr = lane & 15, lg = lane >> 4;
    const int wr = wave >> 1, wc = wave & 1;
    const int bm = blockIdx.y * 64, bn = blockIdx.x * 64;

    f32x4 acc[2][2] = {};
    const int srow = t >> 2, sseg = t & 3;
    const ushort* Arow = A + (size_t)(bm + srow)*Kd + sseg*8;
    const ushort* Brow = Bt + (size_t)(bn + srow)*Kd + sseg*8;
    const int gs = sseg ^ (srow & 3);
    const int swz = lg ^ (lr & 3);

    short8 av = *(const short8*)(Arow);
    short8 bv = *(const short8*)(Brow);

    for (int k0 = 0; k0 < Kd; k0 += 32) {
        __syncthreads();
        *(short8*)&As[srow*32 + gs*8] = av;
        *(short8*)&Bs[srow*32 + gs*8] = bv;
        __syncthreads();
        if (k0 + 32 < Kd) {
            av = *(const short8*)(Arow + k0 + 32);
            bv = *(const short8*)(Brow + k0 + 32);
        }
        short8 af[2], bfr[2];
        #pragma unroll
        for (int m = 0; m < 2; m++)
            af[m] = *(const short8*)&As[(wr*32 + m*16 + lr)*32 + swz*8];
        #pragma unroll
        for (int n = 0; n < 2; n++)
            bfr[n] = *(const short8*)&Bs[(wc*32 + n*16 + lr)*32 + swz*8];
        #pragma unroll
        for (int m = 0; m < 2; m++)
            #pragma unroll
            for (int n = 0; n < 2; n++)
                acc[m][n] = __builtin_amdgcn_mfma_f32_16x16x32_bf16(af[m], bfr[n], acc[m][n], 0, 0, 0);
    }

    #pragma unroll
    for (int m = 0; m < 2; m++) {
        #pragma unroll
        for (int n = 0; n < 2; n++) {
            int gcol = bn + wc*32 + n*16 + lr;
            if (gcol >= N) continue;
            float bz = bias[gcol];
            #pragma unroll
            for (int r = 0; r < 4; r++) {
                size_t grow = bm + wr*32 + m*16 + lg*4 + r;
                float val = acc[m][n][r] + bz;
                if (OUTBF) ((ushort*)C0)[grow*ldc + gcol + coff] = f2bf(val);
                else       ((float*)C0)[grow*ldc + gcol + coff] = val;
            }
        }
    }
}

// ---------------- fused qks + dynamic-kernel GEMM (bf16 ksf) ----------------
__global__ __launch_bounds__(64) void gemm_qksdk(
    const ushort* __restrict__ qkv, const ushort* __restrict__ ksf,
    const ushort* __restrict__ WdkT, const float* __restrict__ bdk,
    float* __restrict__ dynlog)
{
    const int lane = threadIdx.x;
    const int lr = lane & 15, lg = lane >> 4;
    const int r0 = blockIdx.x * 16;
    const int row = r0 + lr;

    f32x4 acc[4] = {};
    for (int ks = 0; ks < RH/32; ks++) {
        int k0 = ks*32 + lg*8;
        short8 qv = *(const short8*)(qkv + (size_t)row*QLD + k0);
        short8 kv = *(const short8*)(ksf + (size_t)row*RH + k0);
        short8 afr;
        #pragma unroll
        for (int j = 0; j < 8; j++)
            afr[j] = (short)f2bf(bf2f((ushort)qv[j]) * bf2f((ushort)kv[j]));
        #pragma unroll
        for (int t4 = 0; t4 < 4; t4++) {
            short8 bfr = *(const short8*)(WdkT + (size_t)(t4*16 + lr)*RH + k0);
            acc[t4] = __builtin_amdgcn_mfma_f32_16x16x32_bf16(afr, bfr, acc[t4], 0, 0, 0);
        }
    }
    #pragma unroll
    for (int t4 = 0; t4 < 4; t4++) {
        int n = t4*16 + lr;
        if (n >= KNH) continue;
        float bz = bdk[n];
        #pragma unroll
        for (int r = 0; r < 4; r++)
            dynlog[(size_t)(r0 + lg*4 + r)*KNH + n] = acc[t4][r] + bz;
    }
}

// ---------------- fused attention (bf16 qkv input), prefetch-pipelined ----------------
__global__ __launch_bounds__(256) void attn_fused(
    const ushort* __restrict__ qkv, const int* __restrict__ mask,
    float* __restrict__ out0, ushort* __restrict__ attnws)
{
    __shared__ __attribute__((aligned(16))) ushort Ks[64*64];
    __shared__ __attribute__((aligned(16))) ushort Vt[64*64];
    __shared__ __attribute__((aligned(16))) ushort Ps[4][16*64];

    const int b = blockIdx.z, h = blockIdx.y, q0 = blockIdx.x * 64;
    const int t = threadIdx.x;
    const int wave = t >> 6, lane = t & 63;
    const int lr = lane & 15, lg = lane >> 4;

    const ushort* qrow = qkv + (size_t)(b*S + q0 + wave*16 + lr)*QLD + h*HD;
    short8 aQ0 = *(const short8*)(qrow + lg*8);
    short8 aQ1 = *(const short8*)(qrow + 32 + lg*8);

    const int srow = t >> 2;
    const int sseg = t & 3;
    const int* mrow = mask + b*S;
    const ushort* krbase = qkv + RH + (size_t)(b*S + srow)*QLD + h*HD + sseg*16;
    const ushort* vbase  = qkv + 2*RH + (size_t)b*S*QLD + h*HD + srow;

    float lsum[4] = {0.f, 0.f, 0.f, 0.f};

    // ---------------- pass A: softmax denominators ----------------
    short8 kv0 = *(const short8*)(krbase);
    short8 kv1 = *(const short8*)(krbase + 8);
    for (int kc = 0; kc < S; kc += 64) {
        __syncthreads();
        *(short8*)&Ks[SWZ(srow, sseg*16)]     = kv0;
        *(short8*)&Ks[SWZ(srow, sseg*16 + 8)] = kv1;
        __syncthreads();
        if (kc + 64 < S) {       // prefetch next K tile
            const ushort* kr = krbase + (size_t)(kc + 64)*QLD;
            kv0 = *(const short8*)(kr);
            kv1 = *(const short8*)(kr + 8);
        }
        #pragma unroll
        for (int t4 = 0; t4 < 4; t4++) {
            short8 b0 = *(const short8*)&Ks[SWZ(t4*16 + lr, lg*8)];
            short8 b1 = *(const short8*)&Ks[SWZ(t4*16 + lr, 32 + lg*8)];
            f32x4 c = {0.f, 0.f, 0.f, 0.f};
            c = __builtin_amdgcn_mfma_f32_16x16x32_bf16(aQ0, b0, c, 0, 0, 0);
            c = __builtin_amdgcn_mfma_f32_16x16x32_bf16(aQ1, b1, c, 0, 0, 0);
            float add = mrow[kc + t4*16 + lr] ? 0.f : -1e30f;
            #pragma unroll
            for (int r = 0; r < 4; r++)
                lsum[r] += exp2f(c[r]*EXPSCALE + add);
        }
    }
    #pragma unroll
    for (int r = 0; r < 4; r++) {
        #pragma unroll
        for (int off = 1; off < 16; off <<= 1)
            lsum[r] += __shfl_xor(lsum[r], off, 16);
    }
    float inv[4];
    #pragma unroll
    for (int r = 0; r < 4; r++) inv[r] = 1.f / lsum[r];

    // ---------------- pass B: recompute, normalize, write P, PV ----------------
    f32x4 o[4] = {};
    ushort* Psw = &Ps[wave][0];
    const size_t obase = ((size_t)((b*NH + h)*S) + q0 + wave*16) * (size_t)S;

    kv0 = *(const short8*)(krbase);
    kv1 = *(const short8*)(krbase + 8);
    ushort vb[16];
    #pragma unroll
    for (int i = 0; i < 16; i++)
        vb[i] = vbase[(size_t)(sseg*16 + i)*QLD];

    for (int kc = 0; kc < S; kc += 64) {
        __syncthreads();
        *(short8*)&Ks[SWZ(srow, sseg*16)]     = kv0;
        *(short8*)&Ks[SWZ(srow, sseg*16 + 8)] = kv1;
        *(short8*)&Vt[SWZ(srow, sseg*16)]     = *(short8*)&vb[0];
        *(short8*)&Vt[SWZ(srow, sseg*16 + 8)] = *(short8*)&vb[8];
        __syncthreads();
        if (kc + 64 < S) {       // prefetch next K + V^T tiles
            const ushort* kr = krbase + (size_t)(kc + 64)*QLD;
            kv0 = *(const short8*)(kr);
            kv1 = *(const short8*)(kr + 8);
            const ushort* vp = vbase + (size_t)(kc + 64)*QLD;
            #pragma unroll
            for (int i = 0; i < 16; i++)
                vb[i] = vp[(size_t)(sseg*16 + i)*QLD];
        }

        #pragma unroll
        for (int t4 = 0; t4 < 4; t4++) {
            short8 b0 = *(const short8*)&Ks[SWZ(t4*16 + lr, lg*8)];
            short8 b1 = *(const short8*)&Ks[SWZ(t4*16 + lr, 32 + lg*8)];
            f32x4 c = {0.f, 0.f, 0.f, 0.f};
            c = __builtin_amdgcn_mfma_f32_16x16x32_bf16(aQ0, b0, c, 0, 0, 0);
            c = __builtin_amdgcn_mfma_f32_16x16x32_bf16(aQ1, b1, c, 0, 0, 0);
            float add = mrow[kc + t4*16 + lr] ? 0.f : -1e30f;
            #pragma unroll
            for (int r = 0; r < 4; r++) {
                float p = exp2f(c[r]*EXPSCALE + add) * inv[r];
                __builtin_nontemporal_store(p, &out0[obase + (size_t)(lg*4 + r)*S + kc + t4*16 + lr]);
                Psw[SWZ(lg*4 + r, t4*16 + lr)] = f2bf(p);
            }
        }
        #pragma unroll
        for (int kh = 0; kh < 2; kh++) {
            short8 pa = *(const short8*)&Psw[SWZ(lr, kh*32 + lg*8)];
            #pragma unroll
            for (int dt = 0; dt < 4; dt++) {
                short8 vv = *(const short8*)&Vt[SWZ(dt*16 + lr, kh*32 + lg*8)];
                o[dt] = __builtin_amdgcn_mfma_f32_16x16x32_bf16(pa, vv, o[dt], 0, 0, 0);
            }
        }
    }

    #pragma unroll
    for (int dt = 0; dt < 4; dt++)
        #pragma unroll
        for (int r = 0; r < 4; r++)
            attnws[(size_t)(b*S + q0 + wave*16 + lg*4 + r)*RH + h*HD + dt*16 + lr] = f2bf(o[dt][r]);
}

// ---------------- dynamic conv: softmax over 9 taps + conv of v (4 ch/thread) ----------------
__global__ __launch_bounds__(256) void dyn_conv(
    const float* __restrict__ logits, const ushort* __restrict__ qkv,
    ushort* __restrict__ dynout)
{
    int idx = blockIdx.x*256 + threadIdx.x;
    if (idx >= B*S*(RH/4)) return;
    int r4 = (idx % (RH/4))*4;
    int s  = (idx / (RH/4)) % S;
    int b  = idx / ((RH/4)*S);
    int h  = r4 / HD;
    const float* lg = logits + ((size_t)b*S + s)*KNH + h*KW;
    float mx = lg[0];
    #pragma unroll
    for (int kk = 1; kk < KW; kk++) mx = fmaxf(mx, lg[kk]);
    float e[KW], sum = 0.f;
    #pragma unroll
    for (int kk = 0; kk < KW; kk++) { e[kk] = __expf(lg[kk]-mx); sum += e[kk]; }
    float inv = 1.f/sum;
    float acc[4] = {0.f, 0.f, 0.f, 0.f};
    const ushort* vbase = qkv + 2*RH;
    #pragma unroll
    for (int kk = 0; kk < KW; kk++) {
        int sp = s + kk - KW/2;
        if (sp >= 0 && sp < S) {
            const ushort* vp = vbase + (size_t)(b*S + sp)*QLD + r4;
            #pragma unroll
            for (int j = 0; j < 4; j++) acc[j] += bf2f(vp[j]) * e[kk];
        }
    }
    ushort4 o;
    o.x = f2bf(acc[0]*inv); o.y = f2bf(acc[1]*inv);
    o.z = f2bf(acc[2]*inv); o.w = f2bf(acc[3]*inv);
    *(ushort4*)(dynout + ((size_t)b*S + s)*RH + r4) = o;
}

extern "C" void kernel_launch(void* const* d_in, const int* in_sizes, int n_in,
                              void* d_out, int out_size, void* d_ws, size_t ws_size,
                              hipStream_t stream) {
    const float* query = (const float*)d_in[0];
    const int*   mask  = (const int*)d_in[1];
    const float* Wq    = (const float*)d_in[2];
    const float* bq    = (const float*)d_in[3];
    const float* Wk    = (const float*)d_in[4];
    const float* bk    = (const float*)d_in[5];
    const float* Wv    = (const float*)d_in[6];
    const float* bv    = (const float*)d_in[7];
    const float* dw_w  = (const float*)d_in[8];
    const float* dw_b  = (const float*)d_in[9];
    const float* pw_w  = (const float*)d_in[10];
    const float* pw_b  = (const float*)d_in[11];
    const float* Wsa   = (const float*)d_in[12];
    const float* bsa   = (const float*)d_in[13];
    const float* Wdk   = (const float*)d_in[14];
    const float* bdk   = (const float*)d_in[15];
    const float* Wda   = (const float*)d_in[16];
    const float* bda   = (const float*)d_in[17];

    float* out0 = (float*)d_out;                 // attn_wts [B,NH,S,S]
    float* out1 = out0 + (size_t)B*NH*S*S;       // concat [B,S,HID]

    char* wsb = (char*)d_ws;
    size_t off = 0;
    auto alloc = [&](size_t bytes) { char* p = wsb + off; off += (bytes + 255) & ~255ull; return p; };
    ushort* Xbf    = (ushort*)alloc((size_t)B*S*HID*2);
    ushort* qkvbf  = (ushort*)alloc((size_t)B*S*QLD*2);
    ushort* dwbf   = (ushort*)alloc((size_t)B*S*HID*2);
    ushort* ksf    = (ushort*)alloc((size_t)B*S*RH*2);
    ushort* attnbf = (ushort*)alloc((size_t)B*S*RH*2);
    ushort* dynbf  = (ushort*)alloc((size_t)B*S*RH*2);
    float*  dynlog = (float*) alloc((size_t)B*S*KNH*4);
    ushort* WqkvT  = (ushort*)alloc((size_t)QLD*HID*2);
    ushort* pw_bf  = (ushort*)alloc((size_t)RH*HID*2);
    ushort* WsaT   = (ushort*)alloc((size_t)RH*RH*2);
    ushort* WdaT   = (ushort*)alloc((size_t)RH*RH*2);
    ushort* WdkT   = (ushort*)alloc((size_t)128*RH*2);
    float*  bqkv   = (float*) alloc((size_t)QLD*4);

    const int M = B*S;  // 8192

    prep_weights<<<(1524864 + 255)/256, 256, 0, stream>>>(
        Wq, Wk, Wv, bq, bk, bv, pw_w, Wsa, Wda, Wdk,
        WqkvT, pw_bf, WsaT, WdaT, WdkT, bqkv);

    // fused bf16 convert + depthwise conv
    cvt_dw_fused<<<(M*(HID/8) + 255)/256, 256, 0, stream>>>(query, dw_w, dw_b, Xbf, dwbf);

    // fused qkv projection -> bf16 [M, 1152]
    gemm_mfma<true><<<dim3(QLD/128, M/128), 256, 0, stream>>>(
        Xbf, WqkvT, bqkv, qkvbf, QLD, HID, QLD);

    // pointwise conv GEMM -> ksf bf16
    gemm64<true, false><<<dim3(RH/64, M/64), 256, 0, stream>>>(
        dwbf, pw_bf, pw_b, ksf, nullptr, nullptr, nullptr, RH, HID, RH);

    // fused MFMA attention
    attn_fused<<<dim3(S/64, NH, B), 256, 0, stream>>>(qkvbf, mask, out0, attnbf);

    // fused qks + dynamic-kernel logits GEMM
    gemm_qksdk<<<M/16, 64, 0, stream>>>(qkvbf, ksf, WdkT, bdk, dynlog);

    // dynamic conv
    dyn_conv<<<(M*(RH/4) + 255)/256, 256, 0, stream>>>(dynlog, qkvbf, dynbf);

    // dual output projection: out1[:, :384] = attnbf@WsaT, out1[:, 384:] = dynbf@WdaT
    gemm64<false, true><<<dim3(OUTHALF/64, M/64, 2), 256, 0, stream>>>(
        attnbf, WsaT, bsa, out1, dynbf, WdaT, bda, OUTHALF, RH, HID);
}